// Round 7
// baseline (626.387 us; speedup 1.0000x reference)
//
#include <hip/hip_runtime.h>
#include <stdint.h>

#define SEQ 4096
#define DM  1024
#define NB  4
#define QSCALE 0.06f

typedef __attribute__((ext_vector_type(8))) short short8;
typedef __attribute__((ext_vector_type(4))) float floatx4;

__device__ __forceinline__ unsigned short f2bf(float f) {
  union { float f; unsigned int u; } v; v.f = f;
  unsigned int u = v.u;
  u += 0x7FFFu + ((u >> 16) & 1u);
  return (unsigned short)(u >> 16);
}

__device__ __forceinline__ void async16(const void* g, void* l) {
  __builtin_amdgcn_global_load_lds(
      (const __attribute__((address_space(1))) void*)g,
      (__attribute__((address_space(3))) void*)l, 16, 0, 0);
}

// ---------------- fp32 -> bf16 convert: x (8192 blks) + 4 weights (2048 blks) ----------------
__global__ void cvt_all(const float* __restrict__ x, const float* __restrict__ wk,
                        const float* __restrict__ wq, const float* __restrict__ wv,
                        const float* __restrict__ wo, unsigned short* __restrict__ xb,
                        unsigned short* __restrict__ wb) {
  int blk = blockIdx.x;
  const float* src;
  unsigned short* dst;
  int i;
  if (blk < 8192) {
    src = x; dst = xb; i = (blk * 256 + threadIdx.x) * 8;
  } else {
    int w = blk - 8192;
    int sel = w >> 9;
    src = sel == 0 ? wk : sel == 1 ? wq : sel == 2 ? wv : wo;
    dst = wb + sel * 1048576;
    i = ((w & 511) * 256 + threadIdx.x) * 8;
  }
  const float4* p = (const float4*)(src + i);
  float4 a = p[0], b = p[1];
  short8 o;
  o[0] = (short)f2bf(a.x); o[1] = (short)f2bf(a.y);
  o[2] = (short)f2bf(a.z); o[3] = (short)f2bf(a.w);
  o[4] = (short)f2bf(b.x); o[5] = (short)f2bf(b.y);
  o[6] = (short)f2bf(b.z); o[7] = (short)f2bf(b.w);
  *(short8*)(dst + i) = o;
}

// ---------------- 256x256 bf16 GEMM body, C = A * W^T, K=1024 ----------------
// 8 waves (2Mx4N), BK=32, 4 LDS buffers (128 KiB), prefetch depth 3,
// counted vmcnt(8) at K-tile boundaries (never 0 in steady state).
// TWO-PHASE rhythm per tile (m201 idiom) + LDS swizzle (both gated; singles
// measured neutral in r4/r6, combo is the m224/m252 regime):
//   phase A: {ds_read a0,b0 | stage A-halves t+3} barrier lgkm0 schedbar
//            setprio 16xMFMA setprio barrier
//   phase B: {ds_read a1     | stage B-halves t+3} barrier lgkm0 schedbar
//            setprio 16xMFMA setprio  vmcnt(counted) barrier
// Hazards identical to verified r4/r5 ledger: reads hit buf[t&3], staging
// hits buf[(t+3)&3] (disjoint); buf[(t+3)&3] fully consumed before previous
// boundary barrier; vmcnt(8) leaves only {t+2,t+3} loads outstanding.
// Swizzle (both-sides, bitwise-identical data): write chunk (t&3)^((t>>3)&3)
// via pre-swizzled global src; read offset ^= (((lane&15)>>1)&3)<<3.
template <bool OUT_BF16, int MT, int NT, bool DUAL>
__device__ __forceinline__ void gemm_body(
    unsigned short* lds, int bid,
    const unsigned short* __restrict__ A, const unsigned short* __restrict__ W,
    void* __restrict__ C0, void* __restrict__ C1, float a0, float a1, long ldc) {
  const int K = 1024;
  const int NKT = 32;  // K / 32
  int tid = threadIdx.x;
  int lane = tid & 63;
  int wid = tid >> 6;
  int wr = wid >> 2, wc = wid & 3;

  // bijective XCD swizzle, nwg = MT*NT (divisible by 8)
  const int CPX = (MT * NT) >> 3;
  int raw = (bid & 7) * CPX + (bid >> 3);
  int bx = raw % MT;
  int by = raw / MT;
  long brow = (long)bx * 256;
  long bcol = (long)by * 256;

  floatx4 acc[8][4];
#pragma unroll
  for (int i = 0; i < 8; i++)
#pragma unroll
    for (int j = 0; j < 4; j++) acc[i][j] = (floatx4){0.f, 0.f, 0.f, 0.f};

  // staging with pre-swizzled source chunk
  int schunk = (tid & 3) ^ ((tid >> 3) & 3);
  const unsigned short* Ag = A + (brow + (tid >> 2)) * K + schunk * 8;
  const unsigned short* Wg = W + (bcol + (tid >> 2)) * K + schunk * 8;
  unsigned short* ldsW = lds + wid * 512;  // wave-uniform LDS dest base

  int aRd = (wr * 128 + (lane & 15)) * 32 + (lane >> 4) * 8;
  int bRd = (wc * 64 + (lane & 15)) * 32 + (lane >> 4) * 8;
  int rsw = (((lane & 15) >> 1) & 3) << 3;
  aRd ^= rsw;
  bRd ^= rsw;

#pragma unroll
  for (int tt = 0; tt < 3; tt++) {
    unsigned short* d = ldsW + tt * 16384;
    const unsigned short* a = Ag + tt * 32;
    const unsigned short* w = Wg + tt * 32;
    async16(a, d);
    async16(a + 128 * K, d + 4096);
    async16(w, d + 8192);
    async16(w + 128 * K, d + 12288);
  }
  asm volatile("s_waitcnt vmcnt(8)" ::: "memory");
  __builtin_amdgcn_s_barrier();

  for (int t = 0; t < NKT; ++t) {
    const unsigned short* bufA = lds + (t & 3) * 16384;
    const unsigned short* bufB = bufA + 8192;
    short8 a0f[4], b0f[4], a1f[4];
    // ---- phase A ----
#pragma unroll
    for (int mt = 0; mt < 4; mt++)
      a0f[mt] = *(const short8*)(bufA + aRd + mt * 512);
#pragma unroll
    for (int nt = 0; nt < 4; nt++)
      b0f[nt] = *(const short8*)(bufB + bRd + nt * 512);
    if (t + 3 < NKT) {  // stage A-halves of tile t+3
      unsigned short* d = ldsW + ((t + 3) & 3) * 16384;
      const unsigned short* a = Ag + (t + 3) * 32;
      async16(a, d);
      async16(a + 128 * K, d + 4096);
    }
    __builtin_amdgcn_s_barrier();
    asm volatile("s_waitcnt lgkmcnt(0)" ::: "memory");
    __builtin_amdgcn_sched_barrier(0);
    __builtin_amdgcn_s_setprio(1);
#pragma unroll
    for (int mt = 0; mt < 4; mt++)
#pragma unroll
      for (int nt = 0; nt < 4; nt++)
        acc[mt][nt] = __builtin_amdgcn_mfma_f32_16x16x32_bf16(
            a0f[mt], b0f[nt], acc[mt][nt], 0, 0, 0);
    __builtin_amdgcn_s_setprio(0);
    __builtin_amdgcn_s_barrier();
    // ---- phase B ----
#pragma unroll
    for (int mt = 0; mt < 4; mt++)
      a1f[mt] = *(const short8*)(bufA + aRd + 2048 + mt * 512);
    if (t + 3 < NKT) {  // stage B-halves of tile t+3
      unsigned short* d = ldsW + ((t + 3) & 3) * 16384;
      const unsigned short* w = Wg + (t + 3) * 32;
      async16(w, d + 8192);
      async16(w + 128 * K, d + 12288);
    }
    __builtin_amdgcn_s_barrier();
    asm volatile("s_waitcnt lgkmcnt(0)" ::: "memory");
    __builtin_amdgcn_sched_barrier(0);
    __builtin_amdgcn_s_setprio(1);
#pragma unroll
    for (int mt = 0; mt < 4; mt++)
#pragma unroll
      for (int nt = 0; nt < 4; nt++)
        acc[4 + mt][nt] = __builtin_amdgcn_mfma_f32_16x16x32_bf16(
            a1f[mt], b0f[nt], acc[4 + mt][nt], 0, 0, 0);
    __builtin_amdgcn_s_setprio(0);
    if (t < NKT - 3)
      asm volatile("s_waitcnt vmcnt(8)" ::: "memory");
    else if (t == NKT - 3)
      asm volatile("s_waitcnt vmcnt(4)" ::: "memory");
    else
      asm volatile("s_waitcnt vmcnt(0)" ::: "memory");
    __builtin_amdgcn_s_barrier();
  }

  void* Cp;
  float alpha;
  long cc;
  if (DUAL && by >= NT / 2) {
    Cp = C1; alpha = a1; cc = bcol - (long)(NT / 2) * 256;
  } else {
    Cp = C0; alpha = a0; cc = bcol;
  }
  long crow = brow + wr * 128 + (lane >> 4) * 4;
  long ccol = cc + wc * 64 + (lane & 15);
#pragma unroll
  for (int mt = 0; mt < 8; mt++)
#pragma unroll
    for (int nt = 0; nt < 4; nt++)
#pragma unroll
      for (int r = 0; r < 4; r++) {
        float v = acc[mt][nt][r] * alpha;
        long idx = (crow + mt * 16 + r) * ldc + ccol + nt * 16;
        if (OUT_BF16)
          ((unsigned short*)Cp)[idx] = f2bf(v);
        else
          ((float*)Cp)[idx] = v;
      }
}

// fused projections: blocks 0-511 = K+Q (DUAL), 512-767 = Vt
__global__ __launch_bounds__(512, 2) void proj_fused(
    const unsigned short* __restrict__ xb, const unsigned short* __restrict__ Wkb,
    const unsigned short* __restrict__ Wvb, unsigned short* __restrict__ Kb,
    unsigned short* __restrict__ Qb, unsigned short* __restrict__ Vt) {
  __shared__ __align__(16) unsigned short lds[4 * 16384];
  if (blockIdx.x < 512)
    gemm_body<true, 64, 8, true>(lds, blockIdx.x, xb, Wkb, Kb, Qb, 1.0f, QSCALE,
                                 1024);
  else
    gemm_body<true, 4, 64, false>(lds, blockIdx.x - 512, Wvb, xb, Vt, nullptr,
                                  1.0f, 1.0f, (long)NB * SEQ);
}

// output projection y*Wo^T (fp32 out)
__global__ __launch_bounds__(512, 2) void gemm_wo(
    const unsigned short* __restrict__ yb, const unsigned short* __restrict__ Wob,
    float* __restrict__ outY) {
  __shared__ __align__(16) unsigned short lds[4 * 16384];
  gemm_body<false, 64, 4, false>(lds, blockIdx.x, yb, Wob, outY, nullptr, 1.0f,
                                 1.0f, 1024);
}

// ---------------- banded logits via the same 256x256 pipeline ----------------
// grid (16 n-tiles, 3 m-offsets {-256,0,+256}, NB); fp32 band-masked epilogue.
__global__ __launch_bounds__(512, 2) void logits256(
    const unsigned short* __restrict__ Qb, const unsigned short* __restrict__ Kb,
    float* __restrict__ att) {
  int b = blockIdx.z;
  int n0 = blockIdx.x * 256;
  int m0 = n0 + ((int)blockIdx.y - 1) * 256;
  if (m0 < 0 || m0 >= SEQ) return;
  __shared__ __align__(16) unsigned short lds[4 * 16384];
  const int K = 1024;
  const int NKT = 32;
  int tid = threadIdx.x;
  int lane = tid & 63;
  int wid = tid >> 6;
  int wr = wid >> 2, wc = wid & 3;

  floatx4 acc[8][4];
#pragma unroll
  for (int i = 0; i < 8; i++)
#pragma unroll
    for (int j = 0; j < 4; j++) acc[i][j] = (floatx4){0.f, 0.f, 0.f, 0.f};

  int schunk = (tid & 3) ^ ((tid >> 3) & 3);
  const unsigned short* Ag =
      Qb + ((long)b * SEQ + n0 + (tid >> 2)) * K + schunk * 8;
  const unsigned short* Wg =
      Kb + ((long)b * SEQ + m0 + (tid >> 2)) * K + schunk * 8;
  unsigned short* ldsW = lds + wid * 512;

  int aRd = (wr * 128 + (lane & 15)) * 32 + (lane >> 4) * 8;
  int bRd = (wc * 64 + (lane & 15)) * 32 + (lane >> 4) * 8;
  int rsw = (((lane & 15) >> 1) & 3) << 3;
  aRd ^= rsw;
  bRd ^= rsw;

#pragma unroll
  for (int tt = 0; tt < 3; tt++) {
    unsigned short* d = ldsW + tt * 16384;
    const unsigned short* a = Ag + tt * 32;
    const unsigned short* w = Wg + tt * 32;
    async16(a, d);
    async16(a + 128 * K, d + 4096);
    async16(w, d + 8192);
    async16(w + 128 * K, d + 12288);
  }
  asm volatile("s_waitcnt vmcnt(8)" ::: "memory");
  __builtin_amdgcn_s_barrier();

  for (int t = 0; t < NKT; ++t) {
    const unsigned short* bufA = lds + (t & 3) * 16384;
    const unsigned short* bufB = bufA + 8192;
    short8 a0f[4], b0f[4], a1f[4];
    // ---- phase A ----
#pragma unroll
    for (int mt = 0; mt < 4; mt++)
      a0f[mt] = *(const short8*)(bufA + aRd + mt * 512);
#pragma unroll
    for (int nt = 0; nt < 4; nt++)
      b0f[nt] = *(const short8*)(bufB + bRd + nt * 512);
    if (t + 3 < NKT) {
      unsigned short* d = ldsW + ((t + 3) & 3) * 16384;
      const unsigned short* a = Ag + (t + 3) * 32;
      async16(a, d);
      async16(a + 128 * K, d + 4096);
    }
    __builtin_amdgcn_s_barrier();
    asm volatile("s_waitcnt lgkmcnt(0)" ::: "memory");
    __builtin_amdgcn_sched_barrier(0);
    __builtin_amdgcn_s_setprio(1);
#pragma unroll
    for (int mt = 0; mt < 4; mt++)
#pragma unroll
      for (int nt = 0; nt < 4; nt++)
        acc[mt][nt] = __builtin_amdgcn_mfma_f32_16x16x32_bf16(
            a0f[mt], b0f[nt], acc[mt][nt], 0, 0, 0);
    __builtin_amdgcn_s_setprio(0);
    __builtin_amdgcn_s_barrier();
    // ---- phase B ----
#pragma unroll
    for (int mt = 0; mt < 4; mt++)
      a1f[mt] = *(const short8*)(bufA + aRd + 2048 + mt * 512);
    if (t + 3 < NKT) {
      unsigned short* d = ldsW + ((t + 3) & 3) * 16384;
      const unsigned short* w = Wg + (t + 3) * 32;
      async16(w, d + 8192);
      async16(w + 128 * K, d + 12288);
    }
    __builtin_amdgcn_s_barrier();
    asm volatile("s_waitcnt lgkmcnt(0)" ::: "memory");
    __builtin_amdgcn_sched_barrier(0);
    __builtin_amdgcn_s_setprio(1);
#pragma unroll
    for (int mt = 0; mt < 4; mt++)
#pragma unroll
      for (int nt = 0; nt < 4; nt++)
        acc[4 + mt][nt] = __builtin_amdgcn_mfma_f32_16x16x32_bf16(
            a1f[mt], b0f[nt], acc[4 + mt][nt], 0, 0, 0);
    __builtin_amdgcn_s_setprio(0);
    if (t < NKT - 3)
      asm volatile("s_waitcnt vmcnt(8)" ::: "memory");
    else if (t == NKT - 3)
      asm volatile("s_waitcnt vmcnt(4)" ::: "memory");
    else
      asm volatile("s_waitcnt vmcnt(0)" ::: "memory");
    __builtin_amdgcn_s_barrier();
  }

  float* attB = att + (long)b * SEQ * SEQ;
  int crow = n0 + wr * 128 + (lane >> 4) * 4;
  int ccol = m0 + wc * 64 + (lane & 15);
#pragma unroll
  for (int mt = 0; mt < 8; mt++)
#pragma unroll
    for (int nt = 0; nt < 4; nt++)
#pragma unroll
      for (int r = 0; r < 4; r++) {
        int row = crow + mt * 16 + r;
        int col = ccol + nt * 16;
        int d = row - col;
        if (d < 256 && d > -256)
          attB[(long)row * SEQ + col] = acc[mt][nt][r];
      }
}

// ---------------- softmax over band, 16 rows/block, LDS band cache ----------------
// attT2[b][nb2][n&255][mi] = att[b][m = (nb2*256)-256+mi][n], 768 mi slots
__global__ __launch_bounds__(256) void softmax_band(
    float* __restrict__ att, unsigned short* __restrict__ attT2) {
  __shared__ float e_lds[16 * 545];
  __shared__ float inv_s[16];
  int blk = blockIdx.x;          // 1024 blocks: 4 batches x 256 row-groups
  int b = blk >> 8;
  int r0 = (blk & 255) * 16;
  int tid = threadIdx.x;
  int row = tid >> 4;            // 0..15 within block
  int t16 = tid & 15;
  int i = r0 + row;
  int jbase = r0 - 272;
  float* arow = att + ((long)b * SEQ + i) * (long)SEQ;

  // phase 1a: load band window into regs, row max
  float raw[34];
  float m = -1e30f;
#pragma unroll
  for (int s = 0; s < 34; s++) {
    int jj = s * 16 + t16;
    int j = jbase + jj;
    bool ok = (j >= 0) && (j < SEQ) && (j >= i - 255) && (j <= i + 255);
    float v = ok ? arow[j] : -1e30f;
    raw[s] = v;
    m = fmaxf(m, v);
  }
#pragma unroll
  for (int off = 8; off; off >>= 1) m = fmaxf(m, __shfl_xor(m, off, 16));

  // phase 1b: exp, store to LDS, row sum
  float sum = 0.f;
#pragma unroll
  for (int s = 0; s < 34; s++) {
    int jj = s * 16 + t16;
    float e = (raw[s] > -1e29f) ? __expf(raw[s] - m) : 0.f;
    e_lds[row * 545 + jj] = e;
    sum += e;
  }
#pragma unroll
  for (int off = 8; off; off >>= 1) sum += __shfl_xor(sum, off, 16);
  float invr = 1.0f / sum;
  if (t16 == 0) inv_s[row] = invr;
  __syncthreads();

  // phase 1c: write full fp32 row (zeros outside band)
  for (int s = 0; s < 64; s++) {
    int j0 = (s * 16 + t16) * 4;
    float4 w;
    float* wp = (float*)&w;
#pragma unroll
    for (int k = 0; k < 4; k++) {
      int j = j0 + k;
      bool ok = (j >= i - 255) && (j <= i + 255);
      int jj = j - jbase;
      jj = jj < 0 ? 0 : (jj > 543 ? 543 : jj);
      wp[k] = ok ? e_lds[row * 545 + jj] * invr : 0.f;
    }
    *(float4*)(arow + j0) = w;
  }

  // phase 2: write attT2 (256-aligned band-compact transpose, 768-wide window)
  int nn = tid >> 4;
  int mi16 = tid & 15;
  int i2 = r0 + mi16;
  float inv2 = inv_s[mi16];
  int Bc = r0 & ~255;            // uniform: [r0, r0+16) never crosses a 256-boundary
  for (int s = 0; s < 48; s++) {
    int n = Bc - 256 + s * 16 + nn;
    if (n < 0 || n >= SEQ) continue;
    int mi = i2 - (n & ~255) + 256;  // always in [0,768)
    bool ok = (n >= i2 - 255) && (n <= i2 + 255);
    int jj = n - jbase;
    jj = jj < 0 ? 0 : (jj > 544 ? 544 : jj);
    float val = ok ? e_lds[mi16 * 545 + jj] * inv2 : 0.f;
    attT2[(((long)b * 16 + (n >> 8)) * 256 + (n & 255)) * 768 + mi] = f2bf(val);
  }
}

// ---------------- y[b][n][o] = sum_m att[b][m][n] * V[b][m][o], 256x256 pipelined ----------------
// A = attT2[b][nb2][256 n][768 mi], B = Vt[o][b*SEQ+m] (m contiguous), K=768.
// Phantom mi windows skipped at the MFMA level (block-uniform guard); staging
// unconditional to keep the vmcnt ledger exact. Same swizzle + 2-phase rhythm.
__global__ __launch_bounds__(512, 2) void attv256(
    const unsigned short* __restrict__ attT2, const unsigned short* __restrict__ Vt,
    unsigned short* __restrict__ yb) {
  __shared__ __align__(16) unsigned short lds[4 * 16384];
  const int KA = 768;
  const int NKT = 24;
  int b = blockIdx.z;
  int nb2 = blockIdx.x;        // 16
  int o0 = blockIdx.y * 256;   // 4
  int N0 = nb2 * 256;
  int tid = threadIdx.x;
  int lane = tid & 63;
  int wid = tid >> 6;
  int wr = wid >> 2, wc = wid & 3;

  floatx4 acc[8][4];
#pragma unroll
  for (int i = 0; i < 8; i++)
#pragma unroll
    for (int j = 0; j < 4; j++) acc[i][j] = (floatx4){0.f, 0.f, 0.f, 0.f};

  int schunk = (tid & 3) ^ ((tid >> 3) & 3);
  const unsigned short* Abase = attT2 + ((long)(b * 16 + nb2) * 256) * KA;
  const unsigned short* Ag = Abase + (long)(tid >> 2) * KA + schunk * 8;
  const unsigned short* Vg =
      Vt + (long)(o0 + (tid >> 2)) * (NB * SEQ) + schunk * 8;
  unsigned short* ldsW = lds + wid * 512;

  int aRd = (wr * 128 + (lane & 15)) * 32 + (lane >> 4) * 8;
  int bRd = (wc * 64 + (lane & 15)) * 32 + (lane >> 4) * 8;
  int rsw = (((lane & 15) >> 1) & 3) << 3;
  aRd ^= rsw;
  bRd ^= rsw;

  auto boff = [&](int t) {
    int mg = N0 - 256 + t * 32;
    int mc = mg < 0 ? 0 : (mg > SEQ - 32 ? SEQ - 32 : mg);
    return (long)b * SEQ + mc;
  };

#pragma unroll
  for (int tt = 0; tt < 3; tt++) {
    unsigned short* d = ldsW + tt * 16384;
    async16(Ag + tt * 32, d);
    async16(Ag + 128 * KA + tt * 32, d + 4096);
    long bo = boff(tt);
    async16(Vg + bo, d + 8192);
    async16(Vg + 128L * (NB * SEQ) + bo, d + 12288);
  }
  asm volatile("s_waitcnt vmcnt(8)" ::: "memory");
  __builtin_amdgcn_s_barrier();

  for (int t = 0; t < NKT; ++t) {
    int mg = N0 - 256 + t * 32;
    bool live = (mg > -32) && (mg < SEQ);   // block-uniform
    const unsigned short* bufA = lds + (t & 3) * 16384;
    const unsigned short* bufB = bufA + 8192;
    short8 a0f[4], b0f[4], a1f[4];
    // ---- phase A ----
#pragma unroll
    for (int mt = 0; mt < 4; mt++)
      a0f[mt] = *(const short8*)(bufA + aRd + mt * 512);
#pragma unroll
    for (int nt = 0; nt < 4; nt++)
      b0f[nt] = *(const short8*)(bufB + bRd + nt * 512);
    if (t + 3 < NKT) {
      unsigned short* d = ldsW + ((t + 3) & 3) * 16384;
      async16(Ag + (t + 3) * 32, d);
      async16(Ag + 128 * KA + (t + 3) * 32, d + 4096);
    }
    __builtin_amdgcn_s_barrier();
    asm volatile("s_waitcnt lgkmcnt(0)" ::: "memory");
    __builtin_amdgcn_sched_barrier(0);
    if (live) {
      __builtin_amdgcn_s_setprio(1);
#pragma unroll
      for (int mt = 0; mt < 4; mt++)
#pragma unroll
        for (int nt = 0; nt < 4; nt++)
          acc[mt][nt] = __builtin_amdgcn_mfma_f32_16x16x32_bf16(
              a0f[mt], b0f[nt], acc[mt][nt], 0, 0, 0);
      __builtin_amdgcn_s_setprio(0);
    }
    __builtin_amdgcn_s_barrier();
    // ---- phase B ----
#pragma unroll
    for (int mt = 0; mt < 4; mt++)
      a1f[mt] = *(const short8*)(bufA + aRd + 2048 + mt * 512);
    if (t + 3 < NKT) {
      unsigned short* d = ldsW + ((t + 3) & 3) * 16384;
      long bo = boff(t + 3);
      async16(Vg + bo, d + 8192);
      async16(Vg + 128L * (NB * SEQ) + bo, d + 12288);
    }
    __builtin_amdgcn_s_barrier();
    asm volatile("s_waitcnt lgkmcnt(0)" ::: "memory");
    __builtin_amdgcn_sched_barrier(0);
    if (live) {
      __builtin_amdgcn_s_setprio(1);
#pragma unroll
      for (int mt = 0; mt < 4; mt++)
#pragma unroll
        for (int nt = 0; nt < 4; nt++)
          acc[4 + mt][nt] = __builtin_amdgcn_mfma_f32_16x16x32_bf16(
              a1f[mt], b0f[nt], acc[4 + mt][nt], 0, 0, 0);
      __builtin_amdgcn_s_setprio(0);
    }
    if (t < NKT - 3)
      asm volatile("s_waitcnt vmcnt(8)" ::: "memory");
    else if (t == NKT - 3)
      asm volatile("s_waitcnt vmcnt(4)" ::: "memory");
    else
      asm volatile("s_waitcnt vmcnt(0)" ::: "memory");
    __builtin_amdgcn_s_barrier();
  }

  long crow = (long)b * SEQ + N0 + wr * 128 + (lane >> 4) * 4;
  int ccol = o0 + wc * 64 + (lane & 15);
#pragma unroll
  for (int mt = 0; mt < 8; mt++)
#pragma unroll
    for (int nt = 0; nt < 4; nt++)
#pragma unroll
      for (int r = 0; r < 4; r++)
        yb[(crow + mt * 16 + r) * DM + ccol + nt * 16] = f2bf(acc[mt][nt][r]);
}

extern "C" void kernel_launch(void* const* d_in, const int* in_sizes, int n_in,
                              void* d_out, int out_size, void* d_ws, size_t ws_size,
                              hipStream_t stream) {
  const float* x  = (const float*)d_in[0];
  const float* Wk = (const float*)d_in[1];
  const float* Wq = (const float*)d_in[2];
  const float* Wv = (const float*)d_in[3];
  const float* Wo = (const float*)d_in[4];
  float* outY = (float*)d_out;
  float* outAtt = outY + (long)NB * SEQ * DM;

  char* ws = (char*)d_ws;
  unsigned short* xb  = (unsigned short*)(ws + 0);            // 32 MiB (reused as yb)
  unsigned short* Kb  = (unsigned short*)(ws + 33554432);     // 32 MiB (reused as attT2)
  unsigned short* Qb  = (unsigned short*)(ws + 67108864);     // 32 MiB
  unsigned short* Vt  = (unsigned short*)(ws + 100663296);    // 32 MiB  Vt[o][b*SEQ+m]
  unsigned short* Wkb = (unsigned short*)(ws + 134217728);    // K,Q,V,O contiguous (8 MiB)
  unsigned short* Wvb = Wkb + 2097152;
  unsigned short* Wob = Wvb + 1048576;
  unsigned short* attT2 = Kb;  // alias: Kb dead after logits256
  unsigned short* yb = xb;     // alias: xb dead after projections

  cvt_all<<<10240, 256, 0, stream>>>(x, Wk, Wq, Wv, Wo, xb, Wkb);
  proj_fused<<<768, 512, 0, stream>>>(xb, Wkb, Wvb, Kb, Qb, Vt);
  logits256<<<dim3(16, 3, NB), 512, 0, stream>>>(Qb, Kb, outAtt);
  softmax_band<<<1024, 256, 0, stream>>>(outAtt, attT2);
  attv256<<<dim3(16, 4, NB), 512, 0, stream>>>(attT2, Vt, yb);
  gemm_wo<<<256, 512, 0, stream>>>(yb, Wob, outY);
}

// Round 8
// 620.169 us; speedup vs baseline: 1.0100x; 1.0100x over previous
//
#include <hip/hip_runtime.h>
#include <stdint.h>

#define SEQ 4096
#define DM  1024
#define NB  4
#define QSCALE 0.06f

typedef __attribute__((ext_vector_type(8))) short short8;
typedef __attribute__((ext_vector_type(4))) float floatx4;

__device__ __forceinline__ unsigned short f2bf(float f) {
  union { float f; unsigned int u; } v; v.f = f;
  unsigned int u = v.u;
  u += 0x7FFFu + ((u >> 16) & 1u);
  return (unsigned short)(u >> 16);
}

__device__ __forceinline__ void async16(const void* g, void* l) {
  __builtin_amdgcn_global_load_lds(
      (const __attribute__((address_space(1))) void*)g,
      (__attribute__((address_space(3))) void*)l, 16, 0, 0);
}

// ---------------- fp32 -> bf16 convert: x (8192 blks) + 4 weights (2048 blks) ----------------
__global__ void cvt_all(const float* __restrict__ x, const float* __restrict__ wk,
                        const float* __restrict__ wq, const float* __restrict__ wv,
                        const float* __restrict__ wo, unsigned short* __restrict__ xb,
                        unsigned short* __restrict__ wb) {
  int blk = blockIdx.x;
  const float* src;
  unsigned short* dst;
  int i;
  if (blk < 8192) {
    src = x; dst = xb; i = (blk * 256 + threadIdx.x) * 8;
  } else {
    int w = blk - 8192;
    int sel = w >> 9;
    src = sel == 0 ? wk : sel == 1 ? wq : sel == 2 ? wv : wo;
    dst = wb + sel * 1048576;
    i = ((w & 511) * 256 + threadIdx.x) * 8;
  }
  const float4* p = (const float4*)(src + i);
  float4 a = p[0], b = p[1];
  short8 o;
  o[0] = (short)f2bf(a.x); o[1] = (short)f2bf(a.y);
  o[2] = (short)f2bf(a.z); o[3] = (short)f2bf(a.w);
  o[4] = (short)f2bf(b.x); o[5] = (short)f2bf(b.y);
  o[6] = (short)f2bf(b.z); o[7] = (short)f2bf(b.w);
  *(short8*)(dst + i) = o;
}

// ---------------- 256x256 bf16 GEMM body, C = A * W^T, K=1024 ----------------
// 8 waves (2Mx4N), BK=32, 4 LDS buffers (128 KiB), prefetch depth 3,
// ONE barrier per K-tile, counted vmcnt(8) (never 0 in steady state).
// Hazards (verified r4-r7): reads hit buf[t&3], staging hits buf[(t+3)&3]
// (disjoint); buf[(t+3)&3] fully consumed before previous boundary barrier;
// vmcnt(8) leaves only {t+2,t+3} loads outstanding => t+1 landed.
// LDS swizzle (both-sides, bitwise-identical): write chunk (t&3)^((t>>3)&3)
// via pre-swizzled global src; read offset ^= (((lane&15)>>1)&3)<<3.
// XCD L2-locality mapping (INNER_BY): each XCD gets CPX consecutive raw ids;
// with raw = bx*NT + by (inner=by), consecutive NT blocks share ONE A-panel
// (0.5 MB: 1 cold + NT-1 L2 hits) and the whole W operand (<=4 MB) stays
// L2-resident. With inner=bx (used when MT<NT, e.g. Vt), the roles swap.
// Rule: inner index = the SMALLER tile-count dimension.
template <bool OUT_BF16, int MT, int NT, bool DUAL, bool INNER_BY>
__device__ __forceinline__ void gemm_body(
    unsigned short* lds, int bid,
    const unsigned short* __restrict__ A, const unsigned short* __restrict__ W,
    void* __restrict__ C0, void* __restrict__ C1, float a0, float a1, long ldc) {
  const int K = 1024;
  const int NKT = 32;  // K / 32
  int tid = threadIdx.x;
  int lane = tid & 63;
  int wid = tid >> 6;
  int wr = wid >> 2, wc = wid & 3;

  // bijective XCD swizzle, nwg = MT*NT (divisible by 8)
  const int CPX = (MT * NT) >> 3;
  int raw = (bid & 7) * CPX + (bid >> 3);
  int bx, by;
  if (INNER_BY) { by = raw % NT; bx = raw / NT; }
  else          { bx = raw % MT; by = raw / MT; }
  long brow = (long)bx * 256;
  long bcol = (long)by * 256;

  floatx4 acc[8][4];
#pragma unroll
  for (int i = 0; i < 8; i++)
#pragma unroll
    for (int j = 0; j < 4; j++) acc[i][j] = (floatx4){0.f, 0.f, 0.f, 0.f};

  // staging with pre-swizzled source chunk
  int schunk = (tid & 3) ^ ((tid >> 3) & 3);
  const unsigned short* Ag = A + (brow + (tid >> 2)) * K + schunk * 8;
  const unsigned short* Wg = W + (bcol + (tid >> 2)) * K + schunk * 8;
  unsigned short* ldsW = lds + wid * 512;  // wave-uniform LDS dest base

  int aRd = (wr * 128 + (lane & 15)) * 32 + (lane >> 4) * 8;
  int bRd = (wc * 64 + (lane & 15)) * 32 + (lane >> 4) * 8;
  int rsw = (((lane & 15) >> 1) & 3) << 3;
  aRd ^= rsw;
  bRd ^= rsw;

#pragma unroll
  for (int tt = 0; tt < 3; tt++) {
    unsigned short* d = ldsW + tt * 16384;
    const unsigned short* a = Ag + tt * 32;
    const unsigned short* w = Wg + tt * 32;
    async16(a, d);
    async16(a + 128 * K, d + 4096);
    async16(w, d + 8192);
    async16(w + 128 * K, d + 12288);
  }
  asm volatile("s_waitcnt vmcnt(8)" ::: "memory");
  __builtin_amdgcn_s_barrier();

  for (int t = 0; t < NKT; ++t) {
    const unsigned short* bufA = lds + (t & 3) * 16384;
    const unsigned short* bufB = bufA + 8192;
    short8 a0f[4], b0f[4], a1f[4];
#pragma unroll
    for (int mt = 0; mt < 4; mt++)
      a0f[mt] = *(const short8*)(bufA + aRd + mt * 512);
#pragma unroll
    for (int nt = 0; nt < 4; nt++)
      b0f[nt] = *(const short8*)(bufB + bRd + nt * 512);
#pragma unroll
    for (int mt = 0; mt < 4; mt++)
      a1f[mt] = *(const short8*)(bufA + aRd + 2048 + mt * 512);
    if (t + 3 < NKT) {  // stage all 4 halves of tile t+3
      unsigned short* d = ldsW + ((t + 3) & 3) * 16384;
      const unsigned short* a = Ag + (t + 3) * 32;
      const unsigned short* w = Wg + (t + 3) * 32;
      async16(a, d);
      async16(a + 128 * K, d + 4096);
      async16(w, d + 8192);
      async16(w + 128 * K, d + 12288);
    }
    __builtin_amdgcn_s_setprio(1);
#pragma unroll
    for (int mt = 0; mt < 4; mt++)
#pragma unroll
      for (int nt = 0; nt < 4; nt++)
        acc[mt][nt] = __builtin_amdgcn_mfma_f32_16x16x32_bf16(
            a0f[mt], b0f[nt], acc[mt][nt], 0, 0, 0);
#pragma unroll
    for (int mt = 0; mt < 4; mt++)
#pragma unroll
      for (int nt = 0; nt < 4; nt++)
        acc[4 + mt][nt] = __builtin_amdgcn_mfma_f32_16x16x32_bf16(
            a1f[mt], b0f[nt], acc[4 + mt][nt], 0, 0, 0);
    __builtin_amdgcn_s_setprio(0);
    if (t < NKT - 3)
      asm volatile("s_waitcnt vmcnt(8)" ::: "memory");
    else if (t == NKT - 3)
      asm volatile("s_waitcnt vmcnt(4)" ::: "memory");
    else
      asm volatile("s_waitcnt vmcnt(0)" ::: "memory");
    __builtin_amdgcn_s_barrier();
  }

  void* Cp;
  float alpha;
  long cc;
  if (DUAL && by >= NT / 2) {
    Cp = C1; alpha = a1; cc = bcol - (long)(NT / 2) * 256;
  } else {
    Cp = C0; alpha = a0; cc = bcol;
  }
  long crow = brow + wr * 128 + (lane >> 4) * 4;
  long ccol = cc + wc * 64 + (lane & 15);
#pragma unroll
  for (int mt = 0; mt < 8; mt++)
#pragma unroll
    for (int nt = 0; nt < 4; nt++)
#pragma unroll
      for (int r = 0; r < 4; r++) {
        float v = acc[mt][nt][r] * alpha;
        long idx = (crow + mt * 16 + r) * ldc + ccol + nt * 16;
        if (OUT_BF16)
          ((unsigned short*)Cp)[idx] = f2bf(v);
        else
          ((float*)Cp)[idx] = v;
      }
}

// fused projections: blocks 0-511 = K+Q (DUAL, inner=by), 512-767 = Vt (inner=bx)
__global__ __launch_bounds__(512, 2) void proj_fused(
    const unsigned short* __restrict__ xb, const unsigned short* __restrict__ Wkb,
    const unsigned short* __restrict__ Wvb, unsigned short* __restrict__ Kb,
    unsigned short* __restrict__ Qb, unsigned short* __restrict__ Vt) {
  __shared__ __align__(16) unsigned short lds[4 * 16384];
  if (blockIdx.x < 512)
    gemm_body<true, 64, 8, true, true>(lds, blockIdx.x, xb, Wkb, Kb, Qb, 1.0f,
                                       QSCALE, 1024);
  else
    gemm_body<true, 4, 64, false, false>(lds, blockIdx.x - 512, Wvb, xb, Vt,
                                         nullptr, 1.0f, 1.0f, (long)NB * SEQ);
}

// output projection y*Wo^T (fp32 out), inner=by
__global__ __launch_bounds__(512, 2) void gemm_wo(
    const unsigned short* __restrict__ yb, const unsigned short* __restrict__ Wob,
    float* __restrict__ outY) {
  __shared__ __align__(16) unsigned short lds[4 * 16384];
  gemm_body<false, 64, 4, false, true>(lds, blockIdx.x, yb, Wob, outY, nullptr,
                                       1.0f, 1.0f, 1024);
}

// ---------------- banded logits via the same 256x256 pipeline ----------------
// grid (16 n-tiles, 3 m-offsets {-256,0,+256}, NB); fp32 band-masked epilogue.
__global__ __launch_bounds__(512, 2) void logits256(
    const unsigned short* __restrict__ Qb, const unsigned short* __restrict__ Kb,
    float* __restrict__ att) {
  int b = blockIdx.z;
  int n0 = blockIdx.x * 256;
  int m0 = n0 + ((int)blockIdx.y - 1) * 256;
  if (m0 < 0 || m0 >= SEQ) return;
  __shared__ __align__(16) unsigned short lds[4 * 16384];
  const int K = 1024;
  const int NKT = 32;
  int tid = threadIdx.x;
  int lane = tid & 63;
  int wid = tid >> 6;
  int wr = wid >> 2, wc = wid & 3;

  floatx4 acc[8][4];
#pragma unroll
  for (int i = 0; i < 8; i++)
#pragma unroll
    for (int j = 0; j < 4; j++) acc[i][j] = (floatx4){0.f, 0.f, 0.f, 0.f};

  int schunk = (tid & 3) ^ ((tid >> 3) & 3);
  const unsigned short* Ag =
      Qb + ((long)b * SEQ + n0 + (tid >> 2)) * K + schunk * 8;
  const unsigned short* Wg =
      Kb + ((long)b * SEQ + m0 + (tid >> 2)) * K + schunk * 8;
  unsigned short* ldsW = lds + wid * 512;

  int aRd = (wr * 128 + (lane & 15)) * 32 + (lane >> 4) * 8;
  int bRd = (wc * 64 + (lane & 15)) * 32 + (lane >> 4) * 8;
  int rsw = (((lane & 15) >> 1) & 3) << 3;
  aRd ^= rsw;
  bRd ^= rsw;

#pragma unroll
  for (int tt = 0; tt < 3; tt++) {
    unsigned short* d = ldsW + tt * 16384;
    const unsigned short* a = Ag + tt * 32;
    const unsigned short* w = Wg + tt * 32;
    async16(a, d);
    async16(a + 128 * K, d + 4096);
    async16(w, d + 8192);
    async16(w + 128 * K, d + 12288);
  }
  asm volatile("s_waitcnt vmcnt(8)" ::: "memory");
  __builtin_amdgcn_s_barrier();

  for (int t = 0; t < NKT; ++t) {
    const unsigned short* bufA = lds + (t & 3) * 16384;
    const unsigned short* bufB = bufA + 8192;
    short8 a0f[4], b0f[4], a1f[4];
#pragma unroll
    for (int mt = 0; mt < 4; mt++)
      a0f[mt] = *(const short8*)(bufA + aRd + mt * 512);
#pragma unroll
    for (int nt = 0; nt < 4; nt++)
      b0f[nt] = *(const short8*)(bufB + bRd + nt * 512);
#pragma unroll
    for (int mt = 0; mt < 4; mt++)
      a1f[mt] = *(const short8*)(bufA + aRd + 2048 + mt * 512);
    if (t + 3 < NKT) {
      unsigned short* d = ldsW + ((t + 3) & 3) * 16384;
      const unsigned short* a = Ag + (t + 3) * 32;
      const unsigned short* w = Wg + (t + 3) * 32;
      async16(a, d);
      async16(a + 128 * K, d + 4096);
      async16(w, d + 8192);
      async16(w + 128 * K, d + 12288);
    }
    __builtin_amdgcn_s_setprio(1);
#pragma unroll
    for (int mt = 0; mt < 4; mt++)
#pragma unroll
      for (int nt = 0; nt < 4; nt++)
        acc[mt][nt] = __builtin_amdgcn_mfma_f32_16x16x32_bf16(
            a0f[mt], b0f[nt], acc[mt][nt], 0, 0, 0);
#pragma unroll
    for (int mt = 0; mt < 4; mt++)
#pragma unroll
      for (int nt = 0; nt < 4; nt++)
        acc[4 + mt][nt] = __builtin_amdgcn_mfma_f32_16x16x32_bf16(
            a1f[mt], b0f[nt], acc[4 + mt][nt], 0, 0, 0);
    __builtin_amdgcn_s_setprio(0);
    if (t < NKT - 3)
      asm volatile("s_waitcnt vmcnt(8)" ::: "memory");
    else if (t == NKT - 3)
      asm volatile("s_waitcnt vmcnt(4)" ::: "memory");
    else
      asm volatile("s_waitcnt vmcnt(0)" ::: "memory");
    __builtin_amdgcn_s_barrier();
  }

  float* attB = att + (long)b * SEQ * SEQ;
  int crow = n0 + wr * 128 + (lane >> 4) * 4;
  int ccol = m0 + wc * 64 + (lane & 15);
#pragma unroll
  for (int mt = 0; mt < 8; mt++)
#pragma unroll
    for (int nt = 0; nt < 4; nt++)
#pragma unroll
      for (int r = 0; r < 4; r++) {
        int row = crow + mt * 16 + r;
        int col = ccol + nt * 16;
        int d = row - col;
        if (d < 256 && d > -256)
          attB[(long)row * SEQ + col] = acc[mt][nt][r];
      }
}

// ---------------- softmax over band, 16 rows/block, LDS band cache ----------------
// attT2[b][nb2][n&255][mi] = att[b][m = (nb2*256)-256+mi][n], 768 mi slots
__global__ __launch_bounds__(256) void softmax_band(
    float* __restrict__ att, unsigned short* __restrict__ attT2) {
  __shared__ float e_lds[16 * 545];
  __shared__ float inv_s[16];
  int blk = blockIdx.x;          // 1024 blocks: 4 batches x 256 row-groups
  int b = blk >> 8;
  int r0 = (blk & 255) * 16;
  int tid = threadIdx.x;
  int row = tid >> 4;            // 0..15 within block
  int t16 = tid & 15;
  int i = r0 + row;
  int jbase = r0 - 272;
  float* arow = att + ((long)b * SEQ + i) * (long)SEQ;

  // phase 1a: load band window into regs, row max
  float raw[34];
  float m = -1e30f;
#pragma unroll
  for (int s = 0; s < 34; s++) {
    int jj = s * 16 + t16;
    int j = jbase + jj;
    bool ok = (j >= 0) && (j < SEQ) && (j >= i - 255) && (j <= i + 255);
    float v = ok ? arow[j] : -1e30f;
    raw[s] = v;
    m = fmaxf(m, v);
  }
#pragma unroll
  for (int off = 8; off; off >>= 1) m = fmaxf(m, __shfl_xor(m, off, 16));

  // phase 1b: exp, store to LDS, row sum
  float sum = 0.f;
#pragma unroll
  for (int s = 0; s < 34; s++) {
    int jj = s * 16 + t16;
    float e = (raw[s] > -1e29f) ? __expf(raw[s] - m) : 0.f;
    e_lds[row * 545 + jj] = e;
    sum += e;
  }
#pragma unroll
  for (int off = 8; off; off >>= 1) sum += __shfl_xor(sum, off, 16);
  float invr = 1.0f / sum;
  if (t16 == 0) inv_s[row] = invr;
  __syncthreads();

  // phase 1c: write full fp32 row (zeros outside band)
  for (int s = 0; s < 64; s++) {
    int j0 = (s * 16 + t16) * 4;
    float4 w;
    float* wp = (float*)&w;
#pragma unroll
    for (int k = 0; k < 4; k++) {
      int j = j0 + k;
      bool ok = (j >= i - 255) && (j <= i + 255);
      int jj = j - jbase;
      jj = jj < 0 ? 0 : (jj > 543 ? 543 : jj);
      wp[k] = ok ? e_lds[row * 545 + jj] * invr : 0.f;
    }
    *(float4*)(arow + j0) = w;
  }

  // phase 2: write attT2 (256-aligned band-compact transpose, 768-wide window)
  int nn = tid >> 4;
  int mi16 = tid & 15;
  int i2 = r0 + mi16;
  float inv2 = inv_s[mi16];
  int Bc = r0 & ~255;            // uniform: [r0, r0+16) never crosses a 256-boundary
  for (int s = 0; s < 48; s++) {
    int n = Bc - 256 + s * 16 + nn;
    if (n < 0 || n >= SEQ) continue;
    int mi = i2 - (n & ~255) + 256;  // always in [0,768)
    bool ok = (n >= i2 - 255) && (n <= i2 + 255);
    int jj = n - jbase;
    jj = jj < 0 ? 0 : (jj > 544 ? 544 : jj);
    float val = ok ? e_lds[mi16 * 545 + jj] * inv2 : 0.f;
    attT2[(((long)b * 16 + (n >> 8)) * 256 + (n & 255)) * 768 + mi] = f2bf(val);
  }
}

// ---------------- y[b][n][o] = sum_m att[b][m][n] * V[b][m][o], 256x256 pipelined ----------------
// A = attT2[b][nb2][256 n][768 mi], B = Vt[o][b*SEQ+m] (m contiguous), K=768.
// Phantom mi windows skipped at the MFMA level (block-uniform guard); staging
// unconditional to keep the vmcnt ledger exact. Same LDS swizzle as gemm_body.
__global__ __launch_bounds__(512, 2) void attv256(
    const unsigned short* __restrict__ attT2, const unsigned short* __restrict__ Vt,
    unsigned short* __restrict__ yb) {
  __shared__ __align__(16) unsigned short lds[4 * 16384];
  const int KA = 768;
  const int NKT = 24;
  int b = blockIdx.z;
  int nb2 = blockIdx.x;        // 16
  int o0 = blockIdx.y * 256;   // 4
  int N0 = nb2 * 256;
  int tid = threadIdx.x;
  int lane = tid & 63;
  int wid = tid >> 6;
  int wr = wid >> 2, wc = wid & 3;

  floatx4 acc[8][4];
#pragma unroll
  for (int i = 0; i < 8; i++)
#pragma unroll
    for (int j = 0; j < 4; j++) acc[i][j] = (floatx4){0.f, 0.f, 0.f, 0.f};

  int schunk = (tid & 3) ^ ((tid >> 3) & 3);
  const unsigned short* Abase = attT2 + ((long)(b * 16 + nb2) * 256) * KA;
  const unsigned short* Ag = Abase + (long)(tid >> 2) * KA + schunk * 8;
  const unsigned short* Vg =
      Vt + (long)(o0 + (tid >> 2)) * (NB * SEQ) + schunk * 8;
  unsigned short* ldsW = lds + wid * 512;

  int aRd = (wr * 128 + (lane & 15)) * 32 + (lane >> 4) * 8;
  int bRd = (wc * 64 + (lane & 15)) * 32 + (lane >> 4) * 8;
  int rsw = (((lane & 15) >> 1) & 3) << 3;
  aRd ^= rsw;
  bRd ^= rsw;

  auto boff = [&](int t) {
    int mg = N0 - 256 + t * 32;
    int mc = mg < 0 ? 0 : (mg > SEQ - 32 ? SEQ - 32 : mg);
    return (long)b * SEQ + mc;
  };

#pragma unroll
  for (int tt = 0; tt < 3; tt++) {
    unsigned short* d = ldsW + tt * 16384;
    async16(Ag + tt * 32, d);
    async16(Ag + 128 * KA + tt * 32, d + 4096);
    long bo = boff(tt);
    async16(Vg + bo, d + 8192);
    async16(Vg + 128L * (NB * SEQ) + bo, d + 12288);
  }
  asm volatile("s_waitcnt vmcnt(8)" ::: "memory");
  __builtin_amdgcn_s_barrier();

  for (int t = 0; t < NKT; ++t) {
    int mg = N0 - 256 + t * 32;
    bool live = (mg > -32) && (mg < SEQ);   // block-uniform
    const unsigned short* bufA = lds + (t & 3) * 16384;
    const unsigned short* bufB = bufA + 8192;
    short8 a0f[4], b0f[4], a1f[4];
#pragma unroll
    for (int mt = 0; mt < 4; mt++)
      a0f[mt] = *(const short8*)(bufA + aRd + mt * 512);
#pragma unroll
    for (int nt = 0; nt < 4; nt++)
      b0f[nt] = *(const short8*)(bufB + bRd + nt * 512);
#pragma unroll
    for (int mt = 0; mt < 4; mt++)
      a1f[mt] = *(const short8*)(bufA + aRd + 2048 + mt * 512);
    if (t + 3 < NKT) {
      unsigned short* d = ldsW + ((t + 3) & 3) * 16384;
      long bo = boff(t + 3);
      async16(Ag + (t + 3) * 32, d);
      async16(Ag + 128 * KA + (t + 3) * 32, d + 4096);
      async16(Vg + bo, d + 8192);
      async16(Vg + 128L * (NB * SEQ) + bo, d + 12288);
    }
    if (live) {
      __builtin_amdgcn_s_setprio(1);
#pragma unroll
      for (int mt = 0; mt < 4; mt++)
#pragma unroll
        for (int nt = 0; nt < 4; nt++)
          acc[mt][nt] = __builtin_amdgcn_mfma_f32_16x16x32_bf16(
              a0f[mt], b0f[nt], acc[mt][nt], 0, 0, 0);
#pragma unroll
      for (int mt = 0; mt < 4; mt++)
#pragma unroll
        for (int nt = 0; nt < 4; nt++)
          acc[4 + mt][nt] = __builtin_amdgcn_mfma_f32_16x16x32_bf16(
              a1f[mt], b0f[nt], acc[4 + mt][nt], 0, 0, 0);
      __builtin_amdgcn_s_setprio(0);
    }
    if (t < NKT - 3)
      asm volatile("s_waitcnt vmcnt(8)" ::: "memory");
    else if (t == NKT - 3)
      asm volatile("s_waitcnt vmcnt(4)" ::: "memory");
    else
      asm volatile("s_waitcnt vmcnt(0)" ::: "memory");
    __builtin_amdgcn_s_barrier();
  }

  long crow = (long)b * SEQ + N0 + wr * 128 + (lane >> 4) * 4;
  int ccol = o0 + wc * 64 + (lane & 15);
#pragma unroll
  for (int mt = 0; mt < 8; mt++)
#pragma unroll
    for (int nt = 0; nt < 4; nt++)
#pragma unroll
      for (int r = 0; r < 4; r++)
        yb[(crow + mt * 16 + r) * DM + ccol + nt * 16] = f2bf(acc[mt][nt][r]);
}

extern "C" void kernel_launch(void* const* d_in, const int* in_sizes, int n_in,
                              void* d_out, int out_size, void* d_ws, size_t ws_size,
                              hipStream_t stream) {
  const float* x  = (const float*)d_in[0];
  const float* Wk = (const float*)d_in[1];
  const float* Wq = (const float*)d_in[2];
  const float* Wv = (const float*)d_in[3];
  const float* Wo = (const float*)d_in[4];
  float* outY = (float*)d_out;
  float* outAtt = outY + (long)NB * SEQ * DM;

  char* ws = (char*)d_ws;
  unsigned short* xb  = (unsigned short*)(ws + 0);            // 32 MiB (reused as yb)
  unsigned short* Kb  = (unsigned short*)(ws + 33554432);     // 32 MiB (reused as attT2)
  unsigned short* Qb  = (unsigned short*)(ws + 67108864);     // 32 MiB
  unsigned short* Vt  = (unsigned short*)(ws + 100663296);    // 32 MiB  Vt[o][b*SEQ+m]
  unsigned short* Wkb = (unsigned short*)(ws + 134217728);    // K,Q,V,O contiguous (8 MiB)
  unsigned short* Wvb = Wkb + 2097152;
  unsigned short* Wob = Wvb + 1048576;
  unsigned short* attT2 = Kb;  // alias: Kb dead after logits256
  unsigned short* yb = xb;     // alias: xb dead after projections

  cvt_all<<<10240, 256, 0, stream>>>(x, Wk, Wq, Wv, Wo, xb, Wkb);
  proj_fused<<<768, 512, 0, stream>>>(xb, Wkb, Wvb, Kb, Qb, Vt);
  logits256<<<dim3(16, 3, NB), 512, 0, stream>>>(Qb, Kb, outAtt);
  softmax_band<<<1024, 256, 0, stream>>>(outAtt, attT2);
  attv256<<<dim3(16, 4, NB), 512, 0, stream>>>(attT2, Vt, yb);
  gemm_wo<<<256, 512, 0, stream>>>(yb, Wob, outY);
}

// Round 9
// 596.221 us; speedup vs baseline: 1.0506x; 1.0402x over previous
//
#include <hip/hip_runtime.h>
#include <stdint.h>

#define SEQ 4096
#define DM  1024
#define NB  4
#define QSCALE 0.06f

typedef __attribute__((ext_vector_type(8))) short short8;
typedef __attribute__((ext_vector_type(4))) float floatx4;

__device__ __forceinline__ unsigned short f2bf(float f) {
  union { float f; unsigned int u; } v; v.f = f;
  unsigned int u = v.u;
  u += 0x7FFFu + ((u >> 16) & 1u);
  return (unsigned short)(u >> 16);
}

__device__ __forceinline__ void async16(const void* g, void* l) {
  __builtin_amdgcn_global_load_lds(
      (const __attribute__((address_space(1))) void*)g,
      (__attribute__((address_space(3))) void*)l, 16, 0, 0);
}

// ---------------- fp32 -> bf16 convert: x (8192 blks) + Wo (512 blks) ----------------
__global__ void cvt_all(const float* __restrict__ x, const float* __restrict__ wo,
                        unsigned short* __restrict__ xb,
                        unsigned short* __restrict__ wob) {
  int blk = blockIdx.x;
  const float* src;
  unsigned short* dst;
  int i;
  if (blk < 8192) {
    src = x; dst = xb; i = (blk * 256 + threadIdx.x) * 8;
  } else {
    src = wo; dst = wob; i = ((blk - 8192) * 256 + threadIdx.x) * 8;
  }
  const float4* p = (const float4*)(src + i);
  float4 a = p[0], b = p[1];
  short8 o;
  o[0] = (short)f2bf(a.x); o[1] = (short)f2bf(a.y);
  o[2] = (short)f2bf(a.z); o[3] = (short)f2bf(a.w);
  o[4] = (short)f2bf(b.x); o[5] = (short)f2bf(b.y);
  o[6] = (short)f2bf(b.z); o[7] = (short)f2bf(b.w);
  *(short8*)(dst + i) = o;
}

// ---------------- transposes: WkT/WqT/WvT (fp32 1024^2 -> bf16 T) + xt (bf16 16384x1024 -> T) ----------------
// 64x64 LDS tiles, coalesced both sides; ushort2 stores.
__global__ __launch_bounds__(256) void trans_all(
    const float* __restrict__ wk, const float* __restrict__ wq,
    const float* __restrict__ wv, const unsigned short* __restrict__ xb,
    unsigned short* __restrict__ WkT, unsigned short* __restrict__ WqT,
    unsigned short* __restrict__ WvT, unsigned short* __restrict__ xt) {
  __shared__ float ls[64 * 65];
  __shared__ unsigned short xs[64 * 66];
  int blk = blockIdx.x, tid = threadIdx.x;
  if (blk < 768) {  // weight transpose: dst[d][o] = src[o][d]
    int mat = blk >> 8, t = blk & 255;
    const float* src = mat == 0 ? wk : mat == 1 ? wq : wv;
    unsigned short* dst = mat == 0 ? WkT : mat == 1 ? WqT : WvT;
    int tr = (t >> 4) * 64;  // o block
    int tc = (t & 15) * 64;  // d block
#pragma unroll
    for (int k = 0; k < 16; k++) {
      int idx = k * 256 + tid, r = idx >> 6, c = idx & 63;
      ls[r * 65 + c] = src[(tr + r) * 1024 + tc + c];
    }
    __syncthreads();
#pragma unroll
    for (int k = 0; k < 8; k++) {
      int idx = k * 256 + tid, r = idx >> 5, c2 = (idx & 31) * 2;
      unsigned short e0 = f2bf(ls[c2 * 65 + r]);
      unsigned short e1 = f2bf(ls[(c2 + 1) * 65 + r]);
      *(ushort2*)(dst + (tc + r) * 1024 + tr + c2) = (ushort2){e0, e1};
    }
  } else {  // x transpose: xt[d][bm] = xb[bm][d]
    int t = blk - 768;
    int tr = (t >> 4) * 64;  // bm block (0..16383)
    int tc = (t & 15) * 64;  // d block
#pragma unroll
    for (int k = 0; k < 16; k++) {
      int idx = k * 256 + tid, r = idx >> 6, c = idx & 63;
      xs[r * 66 + c] = xb[(long)(tr + r) * 1024 + tc + c];
    }
    __syncthreads();
#pragma unroll
    for (int k = 0; k < 8; k++) {
      int idx = k * 256 + tid, r = idx >> 5, c2 = (idx & 31) * 2;
      *(ushort2*)(xt + (long)(tc + r) * (NB * SEQ) + tr + c2) =
          (ushort2){xs[c2 * 66 + r], xs[(c2 + 1) * 66 + r]};
    }
  }
}

// ---------------- 256x256 bf16 GEMM body, C = A * W^T, K=1024 ----------------
// 8 waves (2Mx4N), BK=32, 4 LDS buffers (128 KiB), prefetch depth 3,
// ONE barrier per K-tile, counted vmcnt(8) (never 0 in steady state).
// Hazards (verified r4-r8): reads hit buf[t&3], staging hits buf[(t+3)&3]
// (disjoint); buf[(t+3)&3] fully consumed before previous boundary barrier;
// vmcnt(8) leaves only {t+2,t+3} loads outstanding => t+1 landed.
// LDS swizzle (both-sides, bitwise-identical): write chunk (t&3)^((t>>3)&3)
// via pre-swizzled global src; read offset ^= (((lane&15)>>1)&3)<<3.
template <bool OUT_BF16, int MT, int NT, bool DUAL, bool INNER_BY>
__device__ __forceinline__ void gemm_body(
    unsigned short* lds, int bid,
    const unsigned short* __restrict__ A, const unsigned short* __restrict__ W,
    void* __restrict__ C0, void* __restrict__ C1, float a0, float a1, long ldc) {
  const int K = 1024;
  const int NKT = 32;  // K / 32
  int tid = threadIdx.x;
  int lane = tid & 63;
  int wid = tid >> 6;
  int wr = wid >> 2, wc = wid & 3;

  // bijective XCD swizzle, nwg = MT*NT (divisible by 8)
  const int CPX = (MT * NT) >> 3;
  int raw = (bid & 7) * CPX + (bid >> 3);
  int bx, by;
  if (INNER_BY) { by = raw % NT; bx = raw / NT; }
  else          { bx = raw % MT; by = raw / MT; }
  long brow = (long)bx * 256;
  long bcol = (long)by * 256;

  floatx4 acc[8][4];
#pragma unroll
  for (int i = 0; i < 8; i++)
#pragma unroll
    for (int j = 0; j < 4; j++) acc[i][j] = (floatx4){0.f, 0.f, 0.f, 0.f};

  // staging with pre-swizzled source chunk
  int schunk = (tid & 3) ^ ((tid >> 3) & 3);
  const unsigned short* Ag = A + (brow + (tid >> 2)) * K + schunk * 8;
  const unsigned short* Wg = W + (bcol + (tid >> 2)) * K + schunk * 8;
  unsigned short* ldsW = lds + wid * 512;  // wave-uniform LDS dest base

  int aRd = (wr * 128 + (lane & 15)) * 32 + (lane >> 4) * 8;
  int bRd = (wc * 64 + (lane & 15)) * 32 + (lane >> 4) * 8;
  int rsw = (((lane & 15) >> 1) & 3) << 3;
  aRd ^= rsw;
  bRd ^= rsw;

#pragma unroll
  for (int tt = 0; tt < 3; tt++) {
    unsigned short* d = ldsW + tt * 16384;
    const unsigned short* a = Ag + tt * 32;
    const unsigned short* w = Wg + tt * 32;
    async16(a, d);
    async16(a + 128 * K, d + 4096);
    async16(w, d + 8192);
    async16(w + 128 * K, d + 12288);
  }
  asm volatile("s_waitcnt vmcnt(8)" ::: "memory");
  __builtin_amdgcn_s_barrier();

  for (int t = 0; t < NKT; ++t) {
    const unsigned short* bufA = lds + (t & 3) * 16384;
    const unsigned short* bufB = bufA + 8192;
    short8 a0f[4], b0f[4], a1f[4];
#pragma unroll
    for (int mt = 0; mt < 4; mt++)
      a0f[mt] = *(const short8*)(bufA + aRd + mt * 512);
#pragma unroll
    for (int nt = 0; nt < 4; nt++)
      b0f[nt] = *(const short8*)(bufB + bRd + nt * 512);
#pragma unroll
    for (int mt = 0; mt < 4; mt++)
      a1f[mt] = *(const short8*)(bufA + aRd + 2048 + mt * 512);
    if (t + 3 < NKT) {  // stage all 4 halves of tile t+3
      unsigned short* d = ldsW + ((t + 3) & 3) * 16384;
      const unsigned short* a = Ag + (t + 3) * 32;
      const unsigned short* w = Wg + (t + 3) * 32;
      async16(a, d);
      async16(a + 128 * K, d + 4096);
      async16(w, d + 8192);
      async16(w + 128 * K, d + 12288);
    }
    __builtin_amdgcn_s_setprio(1);
#pragma unroll
    for (int mt = 0; mt < 4; mt++)
#pragma unroll
      for (int nt = 0; nt < 4; nt++)
        acc[mt][nt] = __builtin_amdgcn_mfma_f32_16x16x32_bf16(
            a0f[mt], b0f[nt], acc[mt][nt], 0, 0, 0);
#pragma unroll
    for (int mt = 0; mt < 4; mt++)
#pragma unroll
      for (int nt = 0; nt < 4; nt++)
        acc[4 + mt][nt] = __builtin_amdgcn_mfma_f32_16x16x32_bf16(
            a1f[mt], b0f[nt], acc[4 + mt][nt], 0, 0, 0);
    __builtin_amdgcn_s_setprio(0);
    if (t < NKT - 3)
      asm volatile("s_waitcnt vmcnt(8)" ::: "memory");
    else if (t == NKT - 3)
      asm volatile("s_waitcnt vmcnt(4)" ::: "memory");
    else
      asm volatile("s_waitcnt vmcnt(0)" ::: "memory");
    __builtin_amdgcn_s_barrier();
  }

  void* Cp;
  float alpha;
  long cc;
  if (DUAL && by >= NT / 2) {
    Cp = C1; alpha = a1; cc = bcol - (long)(NT / 2) * 256;
  } else {
    Cp = C0; alpha = a0; cc = bcol;
  }
  long crow = brow + wr * 128 + (lane >> 4) * 4;
  long ccol = cc + wc * 64 + (lane & 15);
#pragma unroll
  for (int mt = 0; mt < 8; mt++)
#pragma unroll
    for (int nt = 0; nt < 4; nt++)
#pragma unroll
      for (int r = 0; r < 4; r++) {
        float v = acc[mt][nt][r] * alpha;
        long idx = (crow + mt * 16 + r) * ldc + ccol + nt * 16;
        if (OUT_BF16)
          ((unsigned short*)Cp)[idx] = f2bf(v);
        else
          ((float*)Cp)[idx] = v;
      }
}

// Gt = QSCALE * WkT * WqT^T  (i.e. Gt[d2][d1] = s*sum_o Wk[o,d2]Wq[o,d1]);
// P  = Wob * WvT^T           (P[i][d] = sum_o Wo[i,o]Wv[o,d]).  32 blocks.
__global__ __launch_bounds__(512, 2) void gp_gemm(
    const unsigned short* __restrict__ WkT, const unsigned short* __restrict__ WqT,
    const unsigned short* __restrict__ Wob, const unsigned short* __restrict__ WvT,
    unsigned short* __restrict__ Gt, unsigned short* __restrict__ P) {
  __shared__ __align__(16) unsigned short lds[4 * 16384];
  if (blockIdx.x < 16)
    gemm_body<true, 4, 4, false, false>(lds, blockIdx.x, WkT, WqT, Gt, nullptr,
                                        QSCALE, 1.0f, 1024);
  else
    gemm_body<true, 4, 4, false, false>(lds, blockIdx.x - 16, Wob, WvT, P,
                                        nullptr, 1.0f, 1.0f, 1024);
}

// T = xb * Gt^T  (T[n][d2] = sum_d1 x[n,d1]G[d1,d2]), 256 blocks, bf16 out.
__global__ __launch_bounds__(512, 2) void gemm_T(
    const unsigned short* __restrict__ xb, const unsigned short* __restrict__ Gt,
    unsigned short* __restrict__ Tb) {
  __shared__ __align__(16) unsigned short lds[4 * 16384];
  gemm_body<true, 64, 4, false, true>(lds, blockIdx.x, xb, Gt, Tb, nullptr,
                                      1.0f, 1.0f, 1024);
}

// y = Z * P^T (fp32 out), 256 blocks.
__global__ __launch_bounds__(512, 2) void gemm_Y(
    const unsigned short* __restrict__ Zb, const unsigned short* __restrict__ P,
    float* __restrict__ outY) {
  __shared__ __align__(16) unsigned short lds[4 * 16384];
  gemm_body<false, 64, 4, false, true>(lds, blockIdx.x, Zb, P, outY, nullptr,
                                       1.0f, 1.0f, 1024);
}

// ---------------- banded logits = T * x^T, 256x256 pipeline ----------------
// grid (16 n-tiles, 3 m-offsets {-256,0,+256}, NB); fp32 band-masked epilogue.
__global__ __launch_bounds__(512, 2) void logits256(
    const unsigned short* __restrict__ Tb, const unsigned short* __restrict__ xb,
    float* __restrict__ att) {
  int b = blockIdx.z;
  int n0 = blockIdx.x * 256;
  int m0 = n0 + ((int)blockIdx.y - 1) * 256;
  if (m0 < 0 || m0 >= SEQ) return;
  __shared__ __align__(16) unsigned short lds[4 * 16384];
  const int K = 1024;
  const int NKT = 32;
  int tid = threadIdx.x;
  int lane = tid & 63;
  int wid = tid >> 6;
  int wr = wid >> 2, wc = wid & 3;

  floatx4 acc[8][4];
#pragma unroll
  for (int i = 0; i < 8; i++)
#pragma unroll
    for (int j = 0; j < 4; j++) acc[i][j] = (floatx4){0.f, 0.f, 0.f, 0.f};

  int schunk = (tid & 3) ^ ((tid >> 3) & 3);
  const unsigned short* Ag =
      Tb + ((long)b * SEQ + n0 + (tid >> 2)) * K + schunk * 8;
  const unsigned short* Wg =
      xb + ((long)b * SEQ + m0 + (tid >> 2)) * K + schunk * 8;
  unsigned short* ldsW = lds + wid * 512;

  int aRd = (wr * 128 + (lane & 15)) * 32 + (lane >> 4) * 8;
  int bRd = (wc * 64 + (lane & 15)) * 32 + (lane >> 4) * 8;
  int rsw = (((lane & 15) >> 1) & 3) << 3;
  aRd ^= rsw;
  bRd ^= rsw;

#pragma unroll
  for (int tt = 0; tt < 3; tt++) {
    unsigned short* d = ldsW + tt * 16384;
    const unsigned short* a = Ag + tt * 32;
    const unsigned short* w = Wg + tt * 32;
    async16(a, d);
    async16(a + 128 * K, d + 4096);
    async16(w, d + 8192);
    async16(w + 128 * K, d + 12288);
  }
  asm volatile("s_waitcnt vmcnt(8)" ::: "memory");
  __builtin_amdgcn_s_barrier();

  for (int t = 0; t < NKT; ++t) {
    const unsigned short* bufA = lds + (t & 3) * 16384;
    const unsigned short* bufB = bufA + 8192;
    short8 a0f[4], b0f[4], a1f[4];
#pragma unroll
    for (int mt = 0; mt < 4; mt++)
      a0f[mt] = *(const short8*)(bufA + aRd + mt * 512);
#pragma unroll
    for (int nt = 0; nt < 4; nt++)
      b0f[nt] = *(const short8*)(bufB + bRd + nt * 512);
#pragma unroll
    for (int mt = 0; mt < 4; mt++)
      a1f[mt] = *(const short8*)(bufA + aRd + 2048 + mt * 512);
    if (t + 3 < NKT) {
      unsigned short* d = ldsW + ((t + 3) & 3) * 16384;
      const unsigned short* a = Ag + (t + 3) * 32;
      const unsigned short* w = Wg + (t + 3) * 32;
      async16(a, d);
      async16(a + 128 * K, d + 4096);
      async16(w, d + 8192);
      async16(w + 128 * K, d + 12288);
    }
    __builtin_amdgcn_s_setprio(1);
#pragma unroll
    for (int mt = 0; mt < 4; mt++)
#pragma unroll
      for (int nt = 0; nt < 4; nt++)
        acc[mt][nt] = __builtin_amdgcn_mfma_f32_16x16x32_bf16(
            a0f[mt], b0f[nt], acc[mt][nt], 0, 0, 0);
#pragma unroll
    for (int mt = 0; mt < 4; mt++)
#pragma unroll
      for (int nt = 0; nt < 4; nt++)
        acc[4 + mt][nt] = __builtin_amdgcn_mfma_f32_16x16x32_bf16(
            a1f[mt], b0f[nt], acc[4 + mt][nt], 0, 0, 0);
    __builtin_amdgcn_s_setprio(0);
    if (t < NKT - 3)
      asm volatile("s_waitcnt vmcnt(8)" ::: "memory");
    else if (t == NKT - 3)
      asm volatile("s_waitcnt vmcnt(4)" ::: "memory");
    else
      asm volatile("s_waitcnt vmcnt(0)" ::: "memory");
    __builtin_amdgcn_s_barrier();
  }

  float* attB = att + (long)b * SEQ * SEQ;
  int crow = n0 + wr * 128 + (lane >> 4) * 4;
  int ccol = m0 + wc * 64 + (lane & 15);
#pragma unroll
  for (int mt = 0; mt < 8; mt++)
#pragma unroll
    for (int nt = 0; nt < 4; nt++)
#pragma unroll
      for (int r = 0; r < 4; r++) {
        int row = crow + mt * 16 + r;
        int col = ccol + nt * 16;
        int d = row - col;
        if (d < 256 && d > -256)
          attB[(long)row * SEQ + col] = acc[mt][nt][r];
      }
}

// ---------------- softmax over band, 16 rows/block, LDS band cache ----------------
// attT2[b][nb2][n&255][mi] = att[b][m = (nb2*256)-256+mi][n], 768 mi slots
__global__ __launch_bounds__(256) void softmax_band(
    float* __restrict__ att, unsigned short* __restrict__ attT2) {
  __shared__ float e_lds[16 * 545];
  __shared__ float inv_s[16];
  int blk = blockIdx.x;          // 1024 blocks: 4 batches x 256 row-groups
  int b = blk >> 8;
  int r0 = (blk & 255) * 16;
  int tid = threadIdx.x;
  int row = tid >> 4;            // 0..15 within block
  int t16 = tid & 15;
  int i = r0 + row;
  int jbase = r0 - 272;
  float* arow = att + ((long)b * SEQ + i) * (long)SEQ;

  // phase 1a: load band window into regs, row max
  float raw[34];
  float m = -1e30f;
#pragma unroll
  for (int s = 0; s < 34; s++) {
    int jj = s * 16 + t16;
    int j = jbase + jj;
    bool ok = (j >= 0) && (j < SEQ) && (j >= i - 255) && (j <= i + 255);
    float v = ok ? arow[j] : -1e30f;
    raw[s] = v;
    m = fmaxf(m, v);
  }
#pragma unroll
  for (int off = 8; off; off >>= 1) m = fmaxf(m, __shfl_xor(m, off, 16));

  // phase 1b: exp, store to LDS, row sum
  float sum = 0.f;
#pragma unroll
  for (int s = 0; s < 34; s++) {
    int jj = s * 16 + t16;
    float e = (raw[s] > -1e29f) ? __expf(raw[s] - m) : 0.f;
    e_lds[row * 545 + jj] = e;
    sum += e;
  }
#pragma unroll
  for (int off = 8; off; off >>= 1) sum += __shfl_xor(sum, off, 16);
  float invr = 1.0f / sum;
  if (t16 == 0) inv_s[row] = invr;
  __syncthreads();

  // phase 1c: write full fp32 row (zeros outside band)
  for (int s = 0; s < 64; s++) {
    int j0 = (s * 16 + t16) * 4;
    float4 w;
    float* wp = (float*)&w;
#pragma unroll
    for (int k = 0; k < 4; k++) {
      int j = j0 + k;
      bool ok = (j >= i - 255) && (j <= i + 255);
      int jj = j - jbase;
      jj = jj < 0 ? 0 : (jj > 543 ? 543 : jj);
      wp[k] = ok ? e_lds[row * 545 + jj] * invr : 0.f;
    }
    *(float4*)(arow + j0) = w;
  }

  // phase 2: write attT2 (256-aligned band-compact transpose, 768-wide window)
  int nn = tid >> 4;
  int mi16 = tid & 15;
  int i2 = r0 + mi16;
  float inv2 = inv_s[mi16];
  int Bc = r0 & ~255;            // uniform: [r0, r0+16) never crosses a 256-boundary
  for (int s = 0; s < 48; s++) {
    int n = Bc - 256 + s * 16 + nn;
    if (n < 0 || n >= SEQ) continue;
    int mi = i2 - (n & ~255) + 256;  // always in [0,768)
    bool ok = (n >= i2 - 255) && (n <= i2 + 255);
    int jj = n - jbase;
    jj = jj < 0 ? 0 : (jj > 544 ? 544 : jj);
    float val = ok ? e_lds[mi16 * 545 + jj] * inv2 : 0.f;
    attT2[(((long)b * 16 + (n >> 8)) * 256 + (n & 255)) * 768 + mi] = f2bf(val);
  }
}

// ---------------- Z[b][n][d] = sum_m att[b][m][n] * x[b][m][d], 256x256 pipelined ----------------
// A = attT2[b][nb2][256 n][768 mi], B = xt[d][b*SEQ+m] (m contiguous), K=768.
// Phantom mi windows skipped at the MFMA level (block-uniform guard); staging
// unconditional to keep the vmcnt ledger exact. Same LDS swizzle as gemm_body.
__global__ __launch_bounds__(512, 2) void attv256(
    const unsigned short* __restrict__ attT2, const unsigned short* __restrict__ xt,
    unsigned short* __restrict__ Zb) {
  __shared__ __align__(16) unsigned short lds[4 * 16384];
  const int KA = 768;
  const int NKT = 24;
  int b = blockIdx.z;
  int nb2 = blockIdx.x;        // 16
  int o0 = blockIdx.y * 256;   // 4  (d-tile)
  int N0 = nb2 * 256;
  int tid = threadIdx.x;
  int lane = tid & 63;
  int wid = tid >> 6;
  int wr = wid >> 2, wc = wid & 3;

  floatx4 acc[8][4];
#pragma unroll
  for (int i = 0; i < 8; i++)
#pragma unroll
    for (int j = 0; j < 4; j++) acc[i][j] = (floatx4){0.f, 0.f, 0.f, 0.f};

  int schunk = (tid & 3) ^ ((tid >> 3) & 3);
  const unsigned short* Abase = attT2 + ((long)(b * 16 + nb2) * 256) * KA;
  const unsigned short* Ag = Abase + (long)(tid >> 2) * KA + schunk * 8;
  const unsigned short* Vg =
      xt + (long)(o0 + (tid >> 2)) * (NB * SEQ) + schunk * 8;
  unsigned short* ldsW = lds + wid * 512;

  int aRd = (wr * 128 + (lane & 15)) * 32 + (lane >> 4) * 8;
  int bRd = (wc * 64 + (lane & 15)) * 32 + (lane >> 4) * 8;
  int rsw = (((lane & 15) >> 1) & 3) << 3;
  aRd ^= rsw;
  bRd ^= rsw;

  auto boff = [&](int t) {
    int mg = N0 - 256 + t * 32;
    int mc = mg < 0 ? 0 : (mg > SEQ - 32 ? SEQ - 32 : mg);
    return (long)b * SEQ + mc;
  };

#pragma unroll
  for (int tt = 0; tt < 3; tt++) {
    unsigned short* d = ldsW + tt * 16384;
    async16(Ag + tt * 32, d);
    async16(Ag + 128 * KA + tt * 32, d + 4096);
    long bo = boff(tt);
    async16(Vg + bo, d + 8192);
    async16(Vg + 128L * (NB * SEQ) + bo, d + 12288);
  }
  asm volatile("s_waitcnt vmcnt(8)" ::: "memory");
  __builtin_amdgcn_s_barrier();

  for (int t = 0; t < NKT; ++t) {
    int mg = N0 - 256 + t * 32;
    bool live = (mg > -32) && (mg < SEQ);   // block-uniform
    const unsigned short* bufA = lds + (t & 3) * 16384;
    const unsigned short* bufB = bufA + 8192;
    short8 a0f[4], b0f[4], a1f[4];
#pragma unroll
    for (int mt = 0; mt < 4; mt++)
      a0f[mt] = *(const short8*)(bufA + aRd + mt * 512);
#pragma unroll
    for (int nt = 0; nt < 4; nt++)
      b0f[nt] = *(const short8*)(bufB + bRd + nt * 512);
#pragma unroll
    for (int mt = 0; mt < 4; mt++)
      a1f[mt] = *(const short8*)(bufA + aRd + 2048 + mt * 512);
    if (t + 3 < NKT) {
      unsigned short* d = ldsW + ((t + 3) & 3) * 16384;
      long bo = boff(t + 3);
      async16(Ag + (t + 3) * 32, d);
      async16(Ag + 128 * KA + (t + 3) * 32, d + 4096);
      async16(Vg + bo, d + 8192);
      async16(Vg + 128L * (NB * SEQ) + bo, d + 12288);
    }
    if (live) {
      __builtin_amdgcn_s_setprio(1);
#pragma unroll
      for (int mt = 0; mt < 4; mt++)
#pragma unroll
        for (int nt = 0; nt < 4; nt++)
          acc[mt][nt] = __builtin_amdgcn_mfma_f32_16x16x32_bf16(
              a0f[mt], b0f[nt], acc[mt][nt], 0, 0, 0);
#pragma unroll
      for (int mt = 0; mt < 4; mt++)
#pragma unroll
        for (int nt = 0; nt < 4; nt++)
          acc[4 + mt][nt] = __builtin_amdgcn_mfma_f32_16x16x32_bf16(
              a1f[mt], b0f[nt], acc[4 + mt][nt], 0, 0, 0);
      __builtin_amdgcn_s_setprio(0);
    }
    if (t < NKT - 3)
      asm volatile("s_waitcnt vmcnt(8)" ::: "memory");
    else if (t == NKT - 3)
      asm volatile("s_waitcnt vmcnt(4)" ::: "memory");
    else
      asm volatile("s_waitcnt vmcnt(0)" ::: "memory");
    __builtin_amdgcn_s_barrier();
  }

  long crow = (long)b * SEQ + N0 + wr * 128 + (lane >> 4) * 4;
  int ccol = o0 + wc * 64 + (lane & 15);
#pragma unroll
  for (int mt = 0; mt < 8; mt++)
#pragma unroll
    for (int nt = 0; nt < 4; nt++)
#pragma unroll
      for (int r = 0; r < 4; r++)
        Zb[(crow + mt * 16 + r) * DM + ccol + nt * 16] = f2bf(acc[mt][nt][r]);
}

extern "C" void kernel_launch(void* const* d_in, const int* in_sizes, int n_in,
                              void* d_out, int out_size, void* d_ws, size_t ws_size,
                              hipStream_t stream) {
  const float* x  = (const float*)d_in[0];
  const float* Wk = (const float*)d_in[1];
  const float* Wq = (const float*)d_in[2];
  const float* Wv = (const float*)d_in[3];
  const float* Wo = (const float*)d_in[4];
  float* outY = (float*)d_out;
  float* outAtt = outY + (long)NB * SEQ * DM;

  char* ws = (char*)d_ws;
  unsigned short* xb   = (unsigned short*)(ws + 0);           // 32 MiB (reused as Zb)
  unsigned short* attT2= (unsigned short*)(ws + 33554432);    // 25.2 MiB
  unsigned short* Tb   = (unsigned short*)(ws + 67108864);    // 32 MiB
  unsigned short* xt   = (unsigned short*)(ws + 100663296);   // 32 MiB  xt[d][b*SEQ+m]
  unsigned short* Wob  = (unsigned short*)(ws + 134217728);   // 2 MiB each below
  unsigned short* WkT  = (unsigned short*)(ws + 136314880);
  unsigned short* WqT  = (unsigned short*)(ws + 138412032);
  unsigned short* WvT  = (unsigned short*)(ws + 140509184);
  unsigned short* Gt   = (unsigned short*)(ws + 142606336);
  unsigned short* P    = (unsigned short*)(ws + 144703488);
  unsigned short* Zb = xb;  // alias: xb dead after logits256 (last reader)

  cvt_all<<<8704, 256, 0, stream>>>(x, Wo, xb, Wob);
  trans_all<<<4864, 256, 0, stream>>>(Wk, Wq, Wv, xb, WkT, WqT, WvT, xt);
  gp_gemm<<<32, 512, 0, stream>>>(WkT, WqT, Wob, WvT, Gt, P);
  gemm_T<<<256, 512, 0, stream>>>(xb, Gt, Tb);
  logits256<<<dim3(16, 3, NB), 512, 0, stream>>>(Tb, xb, outAtt);
  softmax_band<<<1024, 256, 0, stream>>>(outAtt, attT2);
  attv256<<<dim3(16, 4, NB), 512, 0, stream>>>(attT2, xt, Zb);
  gemm_Y<<<256, 512, 0, stream>>>(Zb, P, outY);
}

// Round 10
// 593.489 us; speedup vs baseline: 1.0554x; 1.0046x over previous
//
#include <hip/hip_runtime.h>
#include <stdint.h>

#define SEQ 4096
#define DM  1024
#define NB  4
#define QSCALE 0.06f

typedef __attribute__((ext_vector_type(8))) short short8;
typedef __attribute__((ext_vector_type(4))) float floatx4;

__device__ __forceinline__ unsigned short f2bf(float f) {
  union { float f; unsigned int u; } v; v.f = f;
  unsigned int u = v.u;
  u += 0x7FFFu + ((u >> 16) & 1u);
  return (unsigned short)(u >> 16);
}

__device__ __forceinline__ void async16(const void* g, void* l) {
  __builtin_amdgcn_global_load_lds(
      (const __attribute__((address_space(1))) void*)g,
      (__attribute__((address_space(3))) void*)l, 16, 0, 0);
}

// ---------------- fp32 -> bf16 convert: x (8192 blks) + Wo (512 blks) ----------------
__global__ void cvt_all(const float* __restrict__ x, const float* __restrict__ wo,
                        unsigned short* __restrict__ xb,
                        unsigned short* __restrict__ wob) {
  int blk = blockIdx.x;
  const float* src;
  unsigned short* dst;
  int i;
  if (blk < 8192) {
    src = x; dst = xb; i = (blk * 256 + threadIdx.x) * 8;
  } else {
    src = wo; dst = wob; i = ((blk - 8192) * 256 + threadIdx.x) * 8;
  }
  const float4* p = (const float4*)(src + i);
  float4 a = p[0], b = p[1];
  short8 o;
  o[0] = (short)f2bf(a.x); o[1] = (short)f2bf(a.y);
  o[2] = (short)f2bf(a.z); o[3] = (short)f2bf(a.w);
  o[4] = (short)f2bf(b.x); o[5] = (short)f2bf(b.y);
  o[6] = (short)f2bf(b.z); o[7] = (short)f2bf(b.w);
  *(short8*)(dst + i) = o;
}

// ---------------- transposes: WkT/WqT/WvT (fp32 1024^2 -> bf16 T) + xt (bf16 16384x1024 -> T) ----------------
// 64x64 LDS tiles, coalesced both sides; ushort2 stores.
__global__ __launch_bounds__(256) void trans_all(
    const float* __restrict__ wk, const float* __restrict__ wq,
    const float* __restrict__ wv, const unsigned short* __restrict__ xb,
    unsigned short* __restrict__ WkT, unsigned short* __restrict__ WqT,
    unsigned short* __restrict__ WvT, unsigned short* __restrict__ xt) {
  __shared__ float ls[64 * 65];
  __shared__ unsigned short xs[64 * 66];
  int blk = blockIdx.x, tid = threadIdx.x;
  if (blk < 768) {  // weight transpose: dst[d][o] = src[o][d]
    int mat = blk >> 8, t = blk & 255;
    const float* src = mat == 0 ? wk : mat == 1 ? wq : wv;
    unsigned short* dst = mat == 0 ? WkT : mat == 1 ? WqT : WvT;
    int tr = (t >> 4) * 64;  // o block
    int tc = (t & 15) * 64;  // d block
#pragma unroll
    for (int k = 0; k < 16; k++) {
      int idx = k * 256 + tid, r = idx >> 6, c = idx & 63;
      ls[r * 65 + c] = src[(tr + r) * 1024 + tc + c];
    }
    __syncthreads();
#pragma unroll
    for (int k = 0; k < 8; k++) {
      int idx = k * 256 + tid, r = idx >> 5, c2 = (idx & 31) * 2;
      unsigned short e0 = f2bf(ls[c2 * 65 + r]);
      unsigned short e1 = f2bf(ls[(c2 + 1) * 65 + r]);
      *(ushort2*)(dst + (tc + r) * 1024 + tr + c2) = (ushort2){e0, e1};
    }
  } else {  // x transpose: xt[d][bm] = xb[bm][d]
    int t = blk - 768;
    int tr = (t >> 4) * 64;  // bm block (0..16383)
    int tc = (t & 15) * 64;  // d block
#pragma unroll
    for (int k = 0; k < 16; k++) {
      int idx = k * 256 + tid, r = idx >> 6, c = idx & 63;
      xs[r * 66 + c] = xb[(long)(tr + r) * 1024 + tc + c];
    }
    __syncthreads();
#pragma unroll
    for (int k = 0; k < 8; k++) {
      int idx = k * 256 + tid, r = idx >> 5, c2 = (idx & 31) * 2;
      *(ushort2*)(xt + (long)(tc + r) * (NB * SEQ) + tr + c2) =
          (ushort2){xs[c2 * 66 + r], xs[(c2 + 1) * 66 + r]};
    }
  }
}

// ---------------- Gt/P via 128x128 tiles (m97-style body, verified round 0) ----------------
// 128 blocks (vs 32 at 256^2): fixes the 8x CU underfill of the small GEMMs.
// blocks 0-63:  Gt = QSCALE * WkT * WqT^T   (8x8 tiles of 1024^2)
// blocks 64-127: P  = Wob * WvT^T
// Same 16x16x32 MFMA, ascending-K => bitwise-identical to the 256^2 body.
__global__ __launch_bounds__(256) void gp128(
    const unsigned short* __restrict__ WkT, const unsigned short* __restrict__ WqT,
    const unsigned short* __restrict__ Wob, const unsigned short* __restrict__ WvT,
    unsigned short* __restrict__ Gt, unsigned short* __restrict__ P) {
  __shared__ unsigned short sA[128 * 32];
  __shared__ unsigned short sB[128 * 32];
  const int K = 1024;
  int bid = blockIdx.x;
  const unsigned short* A;
  const unsigned short* W;
  unsigned short* C;
  float alpha;
  int t;
  if (bid < 64) { A = WkT; W = WqT; C = Gt; alpha = QSCALE; t = bid; }
  else          { A = Wob; W = WvT; C = P;  alpha = 1.0f;   t = bid - 64; }
  long rowBase = (long)(t >> 3) * 128;
  int colBase = (t & 7) * 128;
  int tid = threadIdx.x;
  int wid = tid >> 6, lane = tid & 63;
  int wr = wid >> 1, wc = wid & 1;

  floatx4 acc[4][4];
#pragma unroll
  for (int i = 0; i < 4; i++)
#pragma unroll
    for (int j = 0; j < 4; j++) acc[i][j] = (floatx4){0.f, 0.f, 0.f, 0.f};

  int c0 = wid * 64 + lane;
  int c1 = c0 + 256;
  const unsigned short* Ag0 = A + (rowBase + (c0 >> 2)) * K + (c0 & 3) * 8;
  const unsigned short* Ag1 = A + (rowBase + (c1 >> 2)) * K + (c1 & 3) * 8;
  const unsigned short* Bg0 = W + ((long)colBase + (c0 >> 2)) * K + (c0 & 3) * 8;
  const unsigned short* Bg1 = W + ((long)colBase + (c1 >> 2)) * K + (c1 & 3) * 8;
  unsigned short* sA0 = sA + (wid * 64) * 8;
  unsigned short* sA1 = sA + (256 + wid * 64) * 8;
  unsigned short* sB0 = sB + (wid * 64) * 8;
  unsigned short* sB1 = sB + (256 + wid * 64) * 8;

  int aRd = (wr * 64 + (lane & 15)) * 32 + (lane >> 4) * 8;
  int bRd = (wc * 64 + (lane & 15)) * 32 + (lane >> 4) * 8;

  for (int ks = 0; ks < K; ks += 32) {
    async16(Ag0 + ks, sA0);
    async16(Ag1 + ks, sA1);
    async16(Bg0 + ks, sB0);
    async16(Bg1 + ks, sB1);
    __syncthreads();
    short8 af[4], bf[4];
#pragma unroll
    for (int mt = 0; mt < 4; mt++) af[mt] = *(const short8*)(sA + aRd + mt * 512);
#pragma unroll
    for (int nt = 0; nt < 4; nt++) bf[nt] = *(const short8*)(sB + bRd + nt * 512);
#pragma unroll
    for (int mt = 0; mt < 4; mt++)
#pragma unroll
      for (int nt = 0; nt < 4; nt++)
        acc[mt][nt] = __builtin_amdgcn_mfma_f32_16x16x32_bf16(
            af[mt], bf[nt], acc[mt][nt], 0, 0, 0);
    __syncthreads();
  }

  long crow = rowBase + wr * 64 + (lane >> 4) * 4;
  int ccol = colBase + wc * 64 + (lane & 15);
#pragma unroll
  for (int mt = 0; mt < 4; mt++)
#pragma unroll
    for (int nt = 0; nt < 4; nt++)
#pragma unroll
      for (int r = 0; r < 4; r++)
        C[(crow + mt * 16 + r) * 1024 + ccol + nt * 16] =
            f2bf(acc[mt][nt][r] * alpha);
}

// ---------------- 256x256 bf16 GEMM body, C = A * W^T, K=1024 ----------------
// 8 waves (2Mx4N), BK=32, 4 LDS buffers (128 KiB), prefetch depth 3,
// ONE barrier per K-tile, counted vmcnt(8) (never 0 in steady state).
// Hazards (verified r4-r9): reads hit buf[t&3], staging hits buf[(t+3)&3]
// (disjoint); buf[(t+3)&3] fully consumed before previous boundary barrier;
// vmcnt(8) leaves only {t+2,t+3} loads outstanding => t+1 landed.
// LDS swizzle (both-sides, bitwise-identical): write chunk (t&3)^((t>>3)&3)
// via pre-swizzled global src; read offset ^= (((lane&15)>>1)&3)<<3.
template <bool OUT_BF16, int MT, int NT, bool DUAL, bool INNER_BY>
__device__ __forceinline__ void gemm_body(
    unsigned short* lds, int bid,
    const unsigned short* __restrict__ A, const unsigned short* __restrict__ W,
    void* __restrict__ C0, void* __restrict__ C1, float a0, float a1, long ldc) {
  const int K = 1024;
  const int NKT = 32;  // K / 32
  int tid = threadIdx.x;
  int lane = tid & 63;
  int wid = tid >> 6;
  int wr = wid >> 2, wc = wid & 3;

  // bijective XCD swizzle, nwg = MT*NT (divisible by 8)
  const int CPX = (MT * NT) >> 3;
  int raw = (bid & 7) * CPX + (bid >> 3);
  int bx, by;
  if (INNER_BY) { by = raw % NT; bx = raw / NT; }
  else          { bx = raw % MT; by = raw / MT; }
  long brow = (long)bx * 256;
  long bcol = (long)by * 256;

  floatx4 acc[8][4];
#pragma unroll
  for (int i = 0; i < 8; i++)
#pragma unroll
    for (int j = 0; j < 4; j++) acc[i][j] = (floatx4){0.f, 0.f, 0.f, 0.f};

  // staging with pre-swizzled source chunk
  int schunk = (tid & 3) ^ ((tid >> 3) & 3);
  const unsigned short* Ag = A + (brow + (tid >> 2)) * K + schunk * 8;
  const unsigned short* Wg = W + (bcol + (tid >> 2)) * K + schunk * 8;
  unsigned short* ldsW = lds + wid * 512;  // wave-uniform LDS dest base

  int aRd = (wr * 128 + (lane & 15)) * 32 + (lane >> 4) * 8;
  int bRd = (wc * 64 + (lane & 15)) * 32 + (lane >> 4) * 8;
  int rsw = (((lane & 15) >> 1) & 3) << 3;
  aRd ^= rsw;
  bRd ^= rsw;

#pragma unroll
  for (int tt = 0; tt < 3; tt++) {
    unsigned short* d = ldsW + tt * 16384;
    const unsigned short* a = Ag + tt * 32;
    const unsigned short* w = Wg + tt * 32;
    async16(a, d);
    async16(a + 128 * K, d + 4096);
    async16(w, d + 8192);
    async16(w + 128 * K, d + 12288);
  }
  asm volatile("s_waitcnt vmcnt(8)" ::: "memory");
  __builtin_amdgcn_s_barrier();

  for (int t = 0; t < NKT; ++t) {
    const unsigned short* bufA = lds + (t & 3) * 16384;
    const unsigned short* bufB = bufA + 8192;
    short8 a0f[4], b0f[4], a1f[4];
#pragma unroll
    for (int mt = 0; mt < 4; mt++)
      a0f[mt] = *(const short8*)(bufA + aRd + mt * 512);
#pragma unroll
    for (int nt = 0; nt < 4; nt++)
      b0f[nt] = *(const short8*)(bufB + bRd + nt * 512);
#pragma unroll
    for (int mt = 0; mt < 4; mt++)
      a1f[mt] = *(const short8*)(bufA + aRd + 2048 + mt * 512);
    if (t + 3 < NKT) {  // stage all 4 halves of tile t+3
      unsigned short* d = ldsW + ((t + 3) & 3) * 16384;
      const unsigned short* a = Ag + (t + 3) * 32;
      const unsigned short* w = Wg + (t + 3) * 32;
      async16(a, d);
      async16(a + 128 * K, d + 4096);
      async16(w, d + 8192);
      async16(w + 128 * K, d + 12288);
    }
    __builtin_amdgcn_s_setprio(1);
#pragma unroll
    for (int mt = 0; mt < 4; mt++)
#pragma unroll
      for (int nt = 0; nt < 4; nt++)
        acc[mt][nt] = __builtin_amdgcn_mfma_f32_16x16x32_bf16(
            a0f[mt], b0f[nt], acc[mt][nt], 0, 0, 0);
#pragma unroll
    for (int mt = 0; mt < 4; mt++)
#pragma unroll
      for (int nt = 0; nt < 4; nt++)
        acc[4 + mt][nt] = __builtin_amdgcn_mfma_f32_16x16x32_bf16(
            a1f[mt], b0f[nt], acc[4 + mt][nt], 0, 0, 0);
    __builtin_amdgcn_s_setprio(0);
    if (t < NKT - 3)
      asm volatile("s_waitcnt vmcnt(8)" ::: "memory");
    else if (t == NKT - 3)
      asm volatile("s_waitcnt vmcnt(4)" ::: "memory");
    else
      asm volatile("s_waitcnt vmcnt(0)" ::: "memory");
    __builtin_amdgcn_s_barrier();
  }

  void* Cp;
  float alpha;
  long cc;
  if (DUAL && by >= NT / 2) {
    Cp = C1; alpha = a1; cc = bcol - (long)(NT / 2) * 256;
  } else {
    Cp = C0; alpha = a0; cc = bcol;
  }
  long crow = brow + wr * 128 + (lane >> 4) * 4;
  long ccol = cc + wc * 64 + (lane & 15);
#pragma unroll
  for (int mt = 0; mt < 8; mt++)
#pragma unroll
    for (int nt = 0; nt < 4; nt++)
#pragma unroll
      for (int r = 0; r < 4; r++) {
        float v = acc[mt][nt][r] * alpha;
        long idx = (crow + mt * 16 + r) * ldc + ccol + nt * 16;
        if (OUT_BF16)
          ((unsigned short*)Cp)[idx] = f2bf(v);
        else
          ((float*)Cp)[idx] = v;
      }
}

// T = xb * Gt^T  (T[n][d2] = sum_d1 x[n,d1]G[d1,d2]), 256 blocks, bf16 out.
__global__ __launch_bounds__(512, 2) void gemm_T(
    const unsigned short* __restrict__ xb, const unsigned short* __restrict__ Gt,
    unsigned short* __restrict__ Tb) {
  __shared__ __align__(16) unsigned short lds[4 * 16384];
  gemm_body<true, 64, 4, false, true>(lds, blockIdx.x, xb, Gt, Tb, nullptr,
                                      1.0f, 1.0f, 1024);
}

// y = Z * P^T (fp32 out), 256 blocks.
__global__ __launch_bounds__(512, 2) void gemm_Y(
    const unsigned short* __restrict__ Zb, const unsigned short* __restrict__ P,
    float* __restrict__ outY) {
  __shared__ __align__(16) unsigned short lds[4 * 16384];
  gemm_body<false, 64, 4, false, true>(lds, blockIdx.x, Zb, P, outY, nullptr,
                                       1.0f, 1.0f, 1024);
}

// ---------------- banded logits = T * x^T, 256x256 pipeline ----------------
// grid (16 n-tiles, 3 m-offsets {-256,0,+256}, NB); fp32 band-masked epilogue.
__global__ __launch_bounds__(512, 2) void logits256(
    const unsigned short* __restrict__ Tb, const unsigned short* __restrict__ xb,
    float* __restrict__ att) {
  int b = blockIdx.z;
  int n0 = blockIdx.x * 256;
  int m0 = n0 + ((int)blockIdx.y - 1) * 256;
  if (m0 < 0 || m0 >= SEQ) return;
  __shared__ __align__(16) unsigned short lds[4 * 16384];
  const int K = 1024;
  const int NKT = 32;
  int tid = threadIdx.x;
  int lane = tid & 63;
  int wid = tid >> 6;
  int wr = wid >> 2, wc = wid & 3;

  floatx4 acc[8][4];
#pragma unroll
  for (int i = 0; i < 8; i++)
#pragma unroll
    for (int j = 0; j < 4; j++) acc[i][j] = (floatx4){0.f, 0.f, 0.f, 0.f};

  int schunk = (tid & 3) ^ ((tid >> 3) & 3);
  const unsigned short* Ag =
      Tb + ((long)b * SEQ + n0 + (tid >> 2)) * K + schunk * 8;
  const unsigned short* Wg =
      xb + ((long)b * SEQ + m0 + (tid >> 2)) * K + schunk * 8;
  unsigned short* ldsW = lds + wid * 512;

  int aRd = (wr * 128 + (lane & 15)) * 32 + (lane >> 4) * 8;
  int bRd = (wc * 64 + (lane & 15)) * 32 + (lane >> 4) * 8;
  int rsw = (((lane & 15) >> 1) & 3) << 3;
  aRd ^= rsw;
  bRd ^= rsw;

#pragma unroll
  for (int tt = 0; tt < 3; tt++) {
    unsigned short* d = ldsW + tt * 16384;
    const unsigned short* a = Ag + tt * 32;
    const unsigned short* w = Wg + tt * 32;
    async16(a, d);
    async16(a + 128 * K, d + 4096);
    async16(w, d + 8192);
    async16(w + 128 * K, d + 12288);
  }
  asm volatile("s_waitcnt vmcnt(8)" ::: "memory");
  __builtin_amdgcn_s_barrier();

  for (int t = 0; t < NKT; ++t) {
    const unsigned short* bufA = lds + (t & 3) * 16384;
    const unsigned short* bufB = bufA + 8192;
    short8 a0f[4], b0f[4], a1f[4];
#pragma unroll
    for (int mt = 0; mt < 4; mt++)
      a0f[mt] = *(const short8*)(bufA + aRd + mt * 512);
#pragma unroll
    for (int nt = 0; nt < 4; nt++)
      b0f[nt] = *(const short8*)(bufB + bRd + nt * 512);
#pragma unroll
    for (int mt = 0; mt < 4; mt++)
      a1f[mt] = *(const short8*)(bufA + aRd + 2048 + mt * 512);
    if (t + 3 < NKT) {
      unsigned short* d = ldsW + ((t + 3) & 3) * 16384;
      const unsigned short* a = Ag + (t + 3) * 32;
      const unsigned short* w = Wg + (t + 3) * 32;
      async16(a, d);
      async16(a + 128 * K, d + 4096);
      async16(w, d + 8192);
      async16(w + 128 * K, d + 12288);
    }
    __builtin_amdgcn_s_setprio(1);
#pragma unroll
    for (int mt = 0; mt < 4; mt++)
#pragma unroll
      for (int nt = 0; nt < 4; nt++)
        acc[mt][nt] = __builtin_amdgcn_mfma_f32_16x16x32_bf16(
            a0f[mt], b0f[nt], acc[mt][nt], 0, 0, 0);
#pragma unroll
    for (int mt = 0; mt < 4; mt++)
#pragma unroll
      for (int nt = 0; nt < 4; nt++)
        acc[4 + mt][nt] = __builtin_amdgcn_mfma_f32_16x16x32_bf16(
            a1f[mt], b0f[nt], acc[4 + mt][nt], 0, 0, 0);
    __builtin_amdgcn_s_setprio(0);
    if (t < NKT - 3)
      asm volatile("s_waitcnt vmcnt(8)" ::: "memory");
    else if (t == NKT - 3)
      asm volatile("s_waitcnt vmcnt(4)" ::: "memory");
    else
      asm volatile("s_waitcnt vmcnt(0)" ::: "memory");
    __builtin_amdgcn_s_barrier();
  }

  float* attB = att + (long)b * SEQ * SEQ;
  int crow = n0 + wr * 128 + (lane >> 4) * 4;
  int ccol = m0 + wc * 64 + (lane & 15);
#pragma unroll
  for (int mt = 0; mt < 8; mt++)
#pragma unroll
    for (int nt = 0; nt < 4; nt++)
#pragma unroll
      for (int r = 0; r < 4; r++) {
        int row = crow + mt * 16 + r;
        int col = ccol + nt * 16;
        int d = row - col;
        if (d < 256 && d > -256)
          attB[(long)row * SEQ + col] = acc[mt][nt][r];
      }
}

// ---------------- softmax over band, 16 rows/block, LDS band cache ----------------
// attT2[b][nb2][n&255][mi] = att[b][m = (nb2*256)-256+mi][n], 768 mi slots
__global__ __launch_bounds__(256) void softmax_band(
    float* __restrict__ att, unsigned short* __restrict__ attT2) {
  __shared__ float e_lds[16 * 545];
  __shared__ float inv_s[16];
  int blk = blockIdx.x;          // 1024 blocks: 4 batches x 256 row-groups
  int b = blk >> 8;
  int r0 = (blk & 255) * 16;
  int tid = threadIdx.x;
  int row = tid >> 4;            // 0..15 within block
  int t16 = tid & 15;
  int i = r0 + row;
  int jbase = r0 - 272;
  float* arow = att + ((long)b * SEQ + i) * (long)SEQ;

  // phase 1a: load band window into regs, row max
  float raw[34];
  float m = -1e30f;
#pragma unroll
  for (int s = 0; s < 34; s++) {
    int jj = s * 16 + t16;
    int j = jbase + jj;
    bool ok = (j >= 0) && (j < SEQ) && (j >= i - 255) && (j <= i + 255);
    float v = ok ? arow[j] : -1e30f;
    raw[s] = v;
    m = fmaxf(m, v);
  }
#pragma unroll
  for (int off = 8; off; off >>= 1) m = fmaxf(m, __shfl_xor(m, off, 16));

  // phase 1b: exp, store to LDS, row sum
  float sum = 0.f;
#pragma unroll
  for (int s = 0; s < 34; s++) {
    int jj = s * 16 + t16;
    float e = (raw[s] > -1e29f) ? __expf(raw[s] - m) : 0.f;
    e_lds[row * 545 + jj] = e;
    sum += e;
  }
#pragma unroll
  for (int off = 8; off; off >>= 1) sum += __shfl_xor(sum, off, 16);
  float invr = 1.0f / sum;
  if (t16 == 0) inv_s[row] = invr;
  __syncthreads();

  // phase 1c: write full fp32 row (zeros outside band)
  for (int s = 0; s < 64; s++) {
    int j0 = (s * 16 + t16) * 4;
    float4 w;
    float* wp = (float*)&w;
#pragma unroll
    for (int k = 0; k < 4; k++) {
      int j = j0 + k;
      bool ok = (j >= i - 255) && (j <= i + 255);
      int jj = j - jbase;
      jj = jj < 0 ? 0 : (jj > 543 ? 543 : jj);
      wp[k] = ok ? e_lds[row * 545 + jj] * invr : 0.f;
    }
    *(float4*)(arow + j0) = w;
  }

  // phase 2: write attT2 (256-aligned band-compact transpose, 768-wide window)
  int nn = tid >> 4;
  int mi16 = tid & 15;
  int i2 = r0 + mi16;
  float inv2 = inv_s[mi16];
  int Bc = r0 & ~255;            // uniform: [r0, r0+16) never crosses a 256-boundary
  for (int s = 0; s < 48; s++) {
    int n = Bc - 256 + s * 16 + nn;
    if (n < 0 || n >= SEQ) continue;
    int mi = i2 - (n & ~255) + 256;  // always in [0,768)
    bool ok = (n >= i2 - 255) && (n <= i2 + 255);
    int jj = n - jbase;
    jj = jj < 0 ? 0 : (jj > 544 ? 544 : jj);
    float val = ok ? e_lds[mi16 * 545 + jj] * inv2 : 0.f;
    attT2[(((long)b * 16 + (n >> 8)) * 256 + (n & 255)) * 768 + mi] = f2bf(val);
  }
}

// ---------------- Z[b][n][d] = sum_m att[b][m][n] * x[b][m][d], 256x256 pipelined ----------------
// A = attT2[b][nb2][256 n][768 mi], B = xt[d][b*SEQ+m] (m contiguous), K=768.
// Phantom mi windows skipped at the MFMA level (block-uniform guard); staging
// unconditional to keep the vmcnt ledger exact. Same LDS swizzle as gemm_body.
__global__ __launch_bounds__(512, 2) void attv256(
    const unsigned short* __restrict__ attT2, const unsigned short* __restrict__ xt,
    unsigned short* __restrict__ Zb) {
  __shared__ __align__(16) unsigned short lds[4 * 16384];
  const int KA = 768;
  const int NKT = 24;
  int b = blockIdx.z;
  int nb2 = blockIdx.x;        // 16
  int o0 = blockIdx.y * 256;   // 4  (d-tile)
  int N0 = nb2 * 256;
  int tid = threadIdx.x;
  int lane = tid & 63;
  int wid = tid >> 6;
  int wr = wid >> 2, wc = wid & 3;

  floatx4 acc[8][4];
#pragma unroll
  for (int i = 0; i < 8; i++)
#pragma unroll
    for (int j = 0; j < 4; j++) acc[i][j] = (floatx4){0.f, 0.f, 0.f, 0.f};

  int schunk = (tid & 3) ^ ((tid >> 3) & 3);
  const unsigned short* Abase = attT2 + ((long)(b * 16 + nb2) * 256) * KA;
  const unsigned short* Ag = Abase + (long)(tid >> 2) * KA + schunk * 8;
  const unsigned short* Vg =
      xt + (long)(o0 + (tid >> 2)) * (NB * SEQ) + schunk * 8;
  unsigned short* ldsW = lds + wid * 512;

  int aRd = (wr * 128 + (lane & 15)) * 32 + (lane >> 4) * 8;
  int bRd = (wc * 64 + (lane & 15)) * 32 + (lane >> 4) * 8;
  int rsw = (((lane & 15) >> 1) & 3) << 3;
  aRd ^= rsw;
  bRd ^= rsw;

  auto boff = [&](int t) {
    int mg = N0 - 256 + t * 32;
    int mc = mg < 0 ? 0 : (mg > SEQ - 32 ? SEQ - 32 : mg);
    return (long)b * SEQ + mc;
  };

#pragma unroll
  for (int tt = 0; tt < 3; tt++) {
    unsigned short* d = ldsW + tt * 16384;
    async16(Ag + tt * 32, d);
    async16(Ag + 128 * KA + tt * 32, d + 4096);
    long bo = boff(tt);
    async16(Vg + bo, d + 8192);
    async16(Vg + 128L * (NB * SEQ) + bo, d + 12288);
  }
  asm volatile("s_waitcnt vmcnt(8)" ::: "memory");
  __builtin_amdgcn_s_barrier();

  for (int t = 0; t < NKT; ++t) {
    int mg = N0 - 256 + t * 32;
    bool live = (mg > -32) && (mg < SEQ);   // block-uniform
    const unsigned short* bufA = lds + (t & 3) * 16384;
    const unsigned short* bufB = bufA + 8192;
    short8 a0f[4], b0f[4], a1f[4];
#pragma unroll
    for (int mt = 0; mt < 4; mt++)
      a0f[mt] = *(const short8*)(bufA + aRd + mt * 512);
#pragma unroll
    for (int nt = 0; nt < 4; nt++)
      b0f[nt] = *(const short8*)(bufB + bRd + nt * 512);
#pragma unroll
    for (int mt = 0; mt < 4; mt++)
      a1f[mt] = *(const short8*)(bufA + aRd + 2048 + mt * 512);
    if (t + 3 < NKT) {
      unsigned short* d = ldsW + ((t + 3) & 3) * 16384;
      long bo = boff(t + 3);
      async16(Ag + (t + 3) * 32, d);
      async16(Ag + 128 * KA + (t + 3) * 32, d + 4096);
      async16(Vg + bo, d + 8192);
      async16(Vg + 128L * (NB * SEQ) + bo, d + 12288);
    }
    if (live) {
      __builtin_amdgcn_s_setprio(1);
#pragma unroll
      for (int mt = 0; mt < 4; mt++)
#pragma unroll
        for (int nt = 0; nt < 4; nt++)
          acc[mt][nt] = __builtin_amdgcn_mfma_f32_16x16x32_bf16(
              a0f[mt], b0f[nt], acc[mt][nt], 0, 0, 0);
#pragma unroll
      for (int mt = 0; mt < 4; mt++)
#pragma unroll
        for (int nt = 0; nt < 4; nt++)
          acc[4 + mt][nt] = __builtin_amdgcn_mfma_f32_16x16x32_bf16(
              a1f[mt], b0f[nt], acc[4 + mt][nt], 0, 0, 0);
      __builtin_amdgcn_s_setprio(0);
    }
    if (t < NKT - 3)
      asm volatile("s_waitcnt vmcnt(8)" ::: "memory");
    else if (t == NKT - 3)
      asm volatile("s_waitcnt vmcnt(4)" ::: "memory");
    else
      asm volatile("s_waitcnt vmcnt(0)" ::: "memory");
    __builtin_amdgcn_s_barrier();
  }

  long crow = (long)b * SEQ + N0 + wr * 128 + (lane >> 4) * 4;
  int ccol = o0 + wc * 64 + (lane & 15);
#pragma unroll
  for (int mt = 0; mt < 8; mt++)
#pragma unroll
    for (int nt = 0; nt < 4; nt++)
#pragma unroll
      for (int r = 0; r < 4; r++)
        Zb[(crow + mt * 16 + r) * DM + ccol + nt * 16] = f2bf(acc[mt][nt][r]);
}

extern "C" void kernel_launch(void* const* d_in, const int* in_sizes, int n_in,
                              void* d_out, int out_size, void* d_ws, size_t ws_size,
                              hipStream_t stream) {
  const float* x  = (const float*)d_in[0];
  const float* Wk = (const float*)d_in[1];
  const float* Wq = (const float*)d_in[2];
  const float* Wv = (const float*)d_in[3];
  const float* Wo = (const float*)d_in[4];
  float* outY = (float*)d_out;
  float* outAtt = outY + (long)NB * SEQ * DM;

  char* ws = (char*)d_ws;
  unsigned short* xb   = (unsigned short*)(ws + 0);           // 32 MiB (reused as Zb)
  unsigned short* attT2= (unsigned short*)(ws + 33554432);    // 25.2 MiB
  unsigned short* Tb   = (unsigned short*)(ws + 67108864);    // 32 MiB
  unsigned short* xt   = (unsigned short*)(ws + 100663296);   // 32 MiB  xt[d][b*SEQ+m]
  unsigned short* Wob  = (unsigned short*)(ws + 134217728);   // 2 MiB each below
  unsigned short* WkT  = (unsigned short*)(ws + 136314880);
  unsigned short* WqT  = (unsigned short*)(ws + 138412032);
  unsigned short* WvT  = (unsigned short*)(ws + 140509184);
  unsigned short* Gt   = (unsigned short*)(ws + 142606336);
  unsigned short* P    = (unsigned short*)(ws + 144703488);
  unsigned short* Zb = xb;  // alias: xb dead after logits256 (last reader)

  cvt_all<<<8704, 256, 0, stream>>>(x, Wo, xb, Wob);
  trans_all<<<4864, 256, 0, stream>>>(Wk, Wq, Wv, xb, WkT, WqT, WvT, xt);
  gp128<<<128, 256, 0, stream>>>(WkT, WqT, Wob, WvT, Gt, P);
  gemm_T<<<256, 512, 0, stream>>>(xb, Gt, Tb);
  logits256<<<dim3(16, 3, NB), 512, 0, stream>>>(Tb, xb, outAtt);
  softmax_band<<<1024, 256, 0, stream>>>(outAtt, attT2);
  attv256<<<dim3(16, 4, NB), 512, 0, stream>>>(attT2, xt, Zb);
  gemm_Y<<<256, 512, 0, stream>>>(Zb, P, outY);
}